// Round 4
// baseline (334.725 us; speedup 1.0000x reference)
//
#include <hip/hip_runtime.h>

#define TTOK   8192
#define BGR    32
#define NNODE  256
#define DIM    128
#define NH     8
#define HD     16
#define NEDGE  262144
#define SCALE_QK 0.25f

// ---------------- GEMM ----------------
struct GemmJob {
  const float*  A1;
  const float*  A2;
  const float2* ss1;
  const float2* ss2;
  const float*  W;
  const float*  bias;
  const float*  res;
  float*        C;
};

// BM=128, BN=64, BK=16, 256 threads, 8x4 per thread.
// AMODE: 0 = A1 (lda=K); 1 = A1+A2 (both [M,128]); 2 = concat(bn(A1,ss1), bn(A2,ss2)) K=256
template<int AMODE, int RELU, int HASRES>
__global__ __launch_bounds__(256) void gemm_k(GemmJob j0, GemmJob j1, GemmJob j2,
                                              int M, int N, int K)
{
  const GemmJob jb = (blockIdx.z == 0) ? j0 : ((blockIdx.z == 1) ? j1 : j2);
  __shared__ float As[16][132];   // [k][m], transposed
  __shared__ float Ws[16][68];    // [k][n]
  const int bm = blockIdx.y * 128;
  const int bn = blockIdx.x * 64;
  const int tid = threadIdx.x;
  const int r0 = (tid >> 4) * 8;   // 0..120
  const int c0 = (tid & 15) * 4;   // 0..60
  float acc[8][4];
  #pragma unroll
  for (int i = 0; i < 8; i++) { acc[i][0]=0.f; acc[i][1]=0.f; acc[i][2]=0.f; acc[i][3]=0.f; }

  const int rr = tid >> 2;        // 0..63
  const int kg = (tid & 3) * 4;   // 0,4,8,12
  const int wk = tid >> 4;        // 0..15
  const int wc = (tid & 15) * 4;  // 0..60

  for (int bk = 0; bk < K; bk += 16) {
    // A tile 128x16 -> As transposed
    #pragma unroll
    for (int half = 0; half < 2; half++) {
      const int row = bm + rr + half * 64;
      const int k0 = bk + kg;
      float4 a;
      if (AMODE == 0) {
        a = *(const float4*)(jb.A1 + (size_t)row * K + k0);
      } else if (AMODE == 1) {
        float4 u = *(const float4*)(jb.A1 + (size_t)row * 128 + k0);
        float4 w = *(const float4*)(jb.A2 + (size_t)row * 128 + k0);
        a = make_float4(u.x + w.x, u.y + w.y, u.z + w.z, u.w + w.w);
      } else {
        if (k0 < 128) {
          float4 u = *(const float4*)(jb.A1 + (size_t)row * 128 + k0);
          float2 s0 = jb.ss1[k0], s1 = jb.ss1[k0+1], s2 = jb.ss1[k0+2], s3 = jb.ss1[k0+3];
          a = make_float4(u.x*s0.x+s0.y, u.y*s1.x+s1.y, u.z*s2.x+s2.y, u.w*s3.x+s3.y);
        } else {
          const int kq = k0 - 128;
          float4 u = *(const float4*)(jb.A2 + (size_t)row * 128 + kq);
          float2 s0 = jb.ss2[kq], s1 = jb.ss2[kq+1], s2 = jb.ss2[kq+2], s3 = jb.ss2[kq+3];
          a = make_float4(u.x*s0.x+s0.y, u.y*s1.x+s1.y, u.z*s2.x+s2.y, u.w*s3.x+s3.y);
        }
      }
      const int rdst = rr + half * 64;
      As[kg+0][rdst] = a.x; As[kg+1][rdst] = a.y; As[kg+2][rdst] = a.z; As[kg+3][rdst] = a.w;
    }
    // W tile 16x64
    {
      float4 w = *(const float4*)(jb.W + (size_t)(bk + wk) * N + bn + wc);
      *(float4*)&Ws[wk][wc] = w;
    }
    __syncthreads();
    #pragma unroll
    for (int kk = 0; kk < 16; kk++) {
      const float4 a0 = *(const float4*)&As[kk][r0];
      const float4 a1 = *(const float4*)&As[kk][r0+4];
      const float4 bv = *(const float4*)&Ws[kk][c0];
      const float av[8] = {a0.x,a0.y,a0.z,a0.w,a1.x,a1.y,a1.z,a1.w};
      #pragma unroll
      for (int i = 0; i < 8; i++) {
        acc[i][0] = fmaf(av[i], bv.x, acc[i][0]);
        acc[i][1] = fmaf(av[i], bv.y, acc[i][1]);
        acc[i][2] = fmaf(av[i], bv.z, acc[i][2]);
        acc[i][3] = fmaf(av[i], bv.w, acc[i][3]);
      }
    }
    __syncthreads();
  }

  const float4 bb = *(const float4*)(jb.bias + bn + c0);
  #pragma unroll
  for (int i = 0; i < 8; i++) {
    const int row = bm + r0 + i;
    float o0 = acc[i][0] + bb.x, o1 = acc[i][1] + bb.y, o2 = acc[i][2] + bb.z, o3 = acc[i][3] + bb.w;
    if (RELU) { o0 = fmaxf(o0,0.f); o1 = fmaxf(o1,0.f); o2 = fmaxf(o2,0.f); o3 = fmaxf(o3,0.f); }
    if (HASRES) {
      float4 r = *(const float4*)(jb.res + (size_t)row * N + bn + c0);
      o0 += r.x; o1 += r.y; o2 += r.z; o3 += r.w;
    }
    *(float4*)(jb.C + (size_t)row * N + bn + c0) = make_float4(o0,o1,o2,o3);
  }
}

// ---------------- Fused attention v3: thread-pair per 2 rows, j-parity split ----------------
__global__ __launch_bounds__(256) void attn3_k(
    const float* __restrict__ q, const float* __restrict__ k, const float* __restrict__ v,
    const float* __restrict__ tptr, float* __restrict__ fc, float* __restrict__ ff,
    float* __restrict__ dout)
{
  const int bh = blockIdx.x;
  const int b = bh >> 3, h = bh & 7;
  __shared__ float Ks[256][16];
  __shared__ float Vs[256][16];
  __shared__ float red[4][2];
  const int tid = threadIdx.x;
  // stage K/V rows (thread t loads row t)
  {
    const float* kr = k + ((size_t)(b*NNODE + tid))*DIM + h*HD;
    const float* vr = v + ((size_t)(b*NNODE + tid))*DIM + h*HD;
    #pragma unroll
    for (int p = 0; p < 4; p++) {
      *(float4*)&Ks[tid][4*p] = *(const float4*)(kr + 4*p);
      *(float4*)&Vs[tid][4*p] = *(const float4*)(vr + 4*p);
    }
  }
  const int pr  = tid >> 1;       // row pair 0..127
  const int par = tid & 1;        // j parity
  const int r0 = pr * 2;
  const float sc = SCALE_QK / tptr[0];
  float qa[16], qb[16];
  {
    const float* qr = q + ((size_t)(b*NNODE + r0))*DIM + h*HD;
    #pragma unroll
    for (int p = 0; p < 4; p++) {
      float4 a = *(const float4*)(qr + 4*p);
      qa[4*p+0]=a.x*sc; qa[4*p+1]=a.y*sc; qa[4*p+2]=a.z*sc; qa[4*p+3]=a.w*sc;
      float4 c = *(const float4*)(qr + DIM + 4*p);
      qb[4*p+0]=c.x*sc; qb[4*p+1]=c.y*sc; qb[4*p+2]=c.z*sc; qb[4*p+3]=c.w*sc;
    }
  }
  __syncthreads();

  // Pass A: exact max/min for both rows over own parity, then pair-combine
  float mxa=-1e30f, mna=1e30f, mxb=-1e30f, mnb=1e30f;
  for (int j = par; j < NNODE; j += 2) {
    const float4 k0 = *(const float4*)&Ks[j][0];
    const float4 k1 = *(const float4*)&Ks[j][4];
    const float4 k2 = *(const float4*)&Ks[j][8];
    const float4 k3 = *(const float4*)&Ks[j][12];
    float sa = qa[0]*k0.x; float sb = qb[0]*k0.x;
    sa = fmaf(qa[1],k0.y,sa); sb = fmaf(qb[1],k0.y,sb);
    sa = fmaf(qa[2],k0.z,sa); sb = fmaf(qb[2],k0.z,sb);
    sa = fmaf(qa[3],k0.w,sa); sb = fmaf(qb[3],k0.w,sb);
    sa = fmaf(qa[4],k1.x,sa); sb = fmaf(qb[4],k1.x,sb);
    sa = fmaf(qa[5],k1.y,sa); sb = fmaf(qb[5],k1.y,sb);
    sa = fmaf(qa[6],k1.z,sa); sb = fmaf(qb[6],k1.z,sb);
    sa = fmaf(qa[7],k1.w,sa); sb = fmaf(qb[7],k1.w,sb);
    sa = fmaf(qa[8],k2.x,sa); sb = fmaf(qb[8],k2.x,sb);
    sa = fmaf(qa[9],k2.y,sa); sb = fmaf(qb[9],k2.y,sb);
    sa = fmaf(qa[10],k2.z,sa); sb = fmaf(qb[10],k2.z,sb);
    sa = fmaf(qa[11],k2.w,sa); sb = fmaf(qb[11],k2.w,sb);
    sa = fmaf(qa[12],k3.x,sa); sb = fmaf(qb[12],k3.x,sb);
    sa = fmaf(qa[13],k3.y,sa); sb = fmaf(qb[13],k3.y,sb);
    sa = fmaf(qa[14],k3.z,sa); sb = fmaf(qb[14],k3.z,sb);
    sa = fmaf(qa[15],k3.w,sa); sb = fmaf(qb[15],k3.w,sb);
    mxa = fmaxf(mxa, sa); mna = fminf(mna, sa);
    mxb = fmaxf(mxb, sb); mnb = fminf(mnb, sb);
  }
  mxa = fmaxf(mxa, __shfl_xor(mxa, 1)); mna = fminf(mna, __shfl_xor(mna, 1));
  mxb = fmaxf(mxb, __shfl_xor(mxb, 1)); mnb = fminf(mnb, __shfl_xor(mnb, 1));

  // Pass B
  float zca=0,zfa=0,Eca=0,Efa=0, zcb=0,zfb=0,Ecb=0,Efb=0;
  float oca[16], ofa[16], ocb[16], ofb[16];
  #pragma unroll
  for (int d = 0; d < 16; d++) { oca[d]=0.f; ofa[d]=0.f; ocb[d]=0.f; ofb[d]=0.f; }
  for (int j = par; j < NNODE; j += 2) {
    const float4 k0 = *(const float4*)&Ks[j][0];
    const float4 k1 = *(const float4*)&Ks[j][4];
    const float4 k2 = *(const float4*)&Ks[j][8];
    const float4 k3 = *(const float4*)&Ks[j][12];
    float sa = qa[0]*k0.x; float sb = qb[0]*k0.x;
    sa = fmaf(qa[1],k0.y,sa); sb = fmaf(qb[1],k0.y,sb);
    sa = fmaf(qa[2],k0.z,sa); sb = fmaf(qb[2],k0.z,sb);
    sa = fmaf(qa[3],k0.w,sa); sb = fmaf(qb[3],k0.w,sb);
    sa = fmaf(qa[4],k1.x,sa); sb = fmaf(qb[4],k1.x,sb);
    sa = fmaf(qa[5],k1.y,sa); sb = fmaf(qb[5],k1.y,sb);
    sa = fmaf(qa[6],k1.z,sa); sb = fmaf(qb[6],k1.z,sb);
    sa = fmaf(qa[7],k1.w,sa); sb = fmaf(qb[7],k1.w,sb);
    sa = fmaf(qa[8],k2.x,sa); sb = fmaf(qb[8],k2.x,sb);
    sa = fmaf(qa[9],k2.y,sa); sb = fmaf(qb[9],k2.y,sb);
    sa = fmaf(qa[10],k2.z,sa); sb = fmaf(qb[10],k2.z,sb);
    sa = fmaf(qa[11],k2.w,sa); sb = fmaf(qb[11],k2.w,sb);
    sa = fmaf(qa[12],k3.x,sa); sb = fmaf(qb[12],k3.x,sb);
    sa = fmaf(qa[13],k3.y,sa); sb = fmaf(qb[13],k3.y,sb);
    sa = fmaf(qa[14],k3.z,sa); sb = fmaf(qb[14],k3.z,sb);
    sa = fmaf(qa[15],k3.w,sa); sb = fmaf(qb[15],k3.w,sb);
    const float eca = __expf(sa - mxa);
    const float efa = __expf(mna - sa);
    const float ecb = __expf(sb - mxb);
    const float efb = __expf(mnb - sb);
    zca += eca; zfa += efa; zcb += ecb; zfb += efb;
    Eca = fmaf(eca, sa, Eca); Efa = fmaf(efa, -sa, Efa);
    Ecb = fmaf(ecb, sb, Ecb); Efb = fmaf(efb, -sb, Efb);
    const float4 v0 = *(const float4*)&Vs[j][0];
    const float4 v1 = *(const float4*)&Vs[j][4];
    const float4 v2 = *(const float4*)&Vs[j][8];
    const float4 v3 = *(const float4*)&Vs[j][12];
    const float vv[16] = {v0.x,v0.y,v0.z,v0.w, v1.x,v1.y,v1.z,v1.w,
                          v2.x,v2.y,v2.z,v2.w, v3.x,v3.y,v3.z,v3.w};
    #pragma unroll
    for (int d = 0; d < 16; d++) {
      oca[d] = fmaf(eca, vv[d], oca[d]);
      ofa[d] = fmaf(efa, vv[d], ofa[d]);
      ocb[d] = fmaf(ecb, vv[d], ocb[d]);
      ofb[d] = fmaf(efb, vv[d], ofb[d]);
    }
  }
  // pair-combine
  zca += __shfl_xor(zca, 1); zfa += __shfl_xor(zfa, 1);
  zcb += __shfl_xor(zcb, 1); zfb += __shfl_xor(zfb, 1);
  Eca += __shfl_xor(Eca, 1); Efa += __shfl_xor(Efa, 1);
  Ecb += __shfl_xor(Ecb, 1); Efb += __shfl_xor(Efb, 1);
  #pragma unroll
  for (int d = 0; d < 16; d++) {
    oca[d] += __shfl_xor(oca[d], 1);
    ofa[d] += __shfl_xor(ofa[d], 1);
    ocb[d] += __shfl_xor(ocb[d], 1);
    ofb[d] += __shfl_xor(ofb[d], 1);
  }
  float entc = 0.f, entf = 0.f;
  if (par == 0) {
    const float rca = 1.f/zca, rfa = 1.f/zfa, rcb = 1.f/zcb, rfb = 1.f/zfb;
    entc = (mxa + __logf(zca) - Eca*rca) + (mxb + __logf(zcb) - Ecb*rcb);
    entf = (-mna + __logf(zfa) - Efa*rfa) + (-mnb + __logf(zfb) - Efb*rfb);
    float* pc = fc + ((size_t)(b*NNODE + r0))*DIM + h*HD;
    float* pf = ff + ((size_t)(b*NNODE + r0))*DIM + h*HD;
    #pragma unroll
    for (int p = 0; p < 4; p++) {
      *(float4*)(pc + 4*p)       = make_float4(oca[4*p]*rca, oca[4*p+1]*rca, oca[4*p+2]*rca, oca[4*p+3]*rca);
      *(float4*)(pc + DIM + 4*p) = make_float4(ocb[4*p]*rcb, ocb[4*p+1]*rcb, ocb[4*p+2]*rcb, ocb[4*p+3]*rcb);
      *(float4*)(pf + 4*p)       = make_float4(ofa[4*p]*rfa, ofa[4*p+1]*rfa, ofa[4*p+2]*rfa, ofa[4*p+3]*rfa);
      *(float4*)(pf + DIM + 4*p) = make_float4(ofb[4*p]*rfb, ofb[4*p+1]*rfb, ofb[4*p+2]*rfb, ofb[4*p+3]*rfb);
    }
  }
  // block-reduce entropies
  #pragma unroll
  for (int off = 1; off < 64; off <<= 1) {
    entc += __shfl_xor(entc, off);
    entf += __shfl_xor(entf, off);
  }
  const int wv = tid >> 6;
  if ((tid & 63) == 0) { red[wv][0] = entc; red[wv][1] = entf; }
  __syncthreads();
  if (tid == 0) {
    const float tc = red[0][0]+red[1][0]+red[2][0]+red[3][0];
    const float tf = red[0][1]+red[1][1]+red[2][1]+red[3][1];
    dout[3145728 + bh] = tc * (1.0f/256.0f);
    dout[3145984 + bh] = tf * (1.0f/256.0f);
  }
}

// ---------------- Edge sigmoid mask (one thread per (edge, head)) + dst histogram ----------------
__global__ __launch_bounds__(256) void edge_k(
    const float* __restrict__ q, const float* __restrict__ k,
    const int* __restrict__ ei, float* __restrict__ maskout, float* __restrict__ emc,
    int* __restrict__ cnt)
{
  const int gt = blockIdx.x * 256 + threadIdx.x;   // 0 .. E*8-1
  const int e = gt >> 3, h = gt & 7;
  const int src = ei[e];
  const int dst = ei[NEDGE + e];
  const float* qr = q + (size_t)src * DIM + h*HD;
  const float* kr = k + (size_t)dst * DIM + h*HD;
  float s = 0.f;
  #pragma unroll
  for (int p = 0; p < 4; p++) {
    float4 a = *(const float4*)(qr + 4*p);
    float4 c = *(const float4*)(kr + 4*p);
    s += a.x*c.x + a.y*c.y + a.z*c.z + a.w*c.w;
  }
  s *= SCALE_QK;
  const float sig = 1.f / (1.f + __expf(-s));
  maskout[gt] = sig;
  float m = sig;
  m += __shfl_xor(m, 1); m += __shfl_xor(m, 2); m += __shfl_xor(m, 4);
  if ((threadIdx.x & 7) == 0) {
    emc[e] = m * 0.125f;
    atomicAdd(&cnt[dst], 1);
  }
}

// ---------------- CSR build: exclusive scan over 8192 dst counters ----------------
__global__ __launch_bounds__(256) void scan_k(const int* __restrict__ cnt,
                                              int* __restrict__ off,
                                              int* __restrict__ cursor)
{
  __shared__ int part[256];
  const int t = threadIdx.x;
  const int base = t * 32;
  int local[32];
  int s = 0;
  #pragma unroll
  for (int i = 0; i < 32; i++) { local[i] = s; s += cnt[base + i]; }
  part[t] = s;
  __syncthreads();
  int pre = 0;
  for (int i = 0; i < t; i++) pre += part[i];
  #pragma unroll
  for (int i = 0; i < 32; i++) {
    const int v = pre + local[i];
    off[base + i] = v;
    cursor[base + i] = v;
  }
  if (t == 255) off[8192] = pre + s;
}

__global__ __launch_bounds__(256) void place_k(const int* __restrict__ ei,
                                               int* __restrict__ cursor,
                                               int* __restrict__ elist)
{
  const int e = blockIdx.x * 256 + threadIdx.x;
  const int d = ei[NEDGE + e];
  const int pos = atomicAdd(&cursor[d], 1);
  elist[pos] = e;
}

// ---------------- GINE gather-aggregate v2: one wave per node ----------------
// Lanes 0-31 process even-indexed CSR entries, lanes 32-63 odd-indexed.
// Each lane owns 4 columns (c4). Combine halves via shfl_xor(.,32).
__global__ __launch_bounds__(256) void gine_gather_k(
    const float* __restrict__ x, const float* __restrict__ ea,
    const int* __restrict__ ei, const float* __restrict__ emc,
    const int* __restrict__ off, const int* __restrict__ elist,
    float* __restrict__ aggrC, float* __restrict__ aggrF)
{
  const int wv = threadIdx.x >> 6, lane = threadIdx.x & 63;
  const int eh = lane >> 5;
  const int c4 = (lane & 31) * 4;
  const int n = blockIdx.x * 4 + wv;
  float4 aC = make_float4(0,0,0,0), aF = make_float4(0,0,0,0);
  int i = off[n] + eh;
  const int end = off[n + 1];
  bool valid = i < end;
  int e0 = 0, s0 = 0; float m0 = 0.f;
  float4 u0 = make_float4(0,0,0,0), w0 = make_float4(0,0,0,0);
  if (valid) {
    e0 = elist[i]; s0 = ei[e0]; m0 = emc[e0];
    u0 = *(const float4*)(x  + (size_t)s0 * DIM + c4);
    w0 = *(const float4*)(ea + (size_t)e0 * DIM + c4);
  }
  while (valid) {
    const int i1 = i + 2;
    const bool v1 = i1 < end;
    float4 u1 = make_float4(0,0,0,0), w1 = make_float4(0,0,0,0);
    float m1 = 0.f;
    if (v1) {
      const int e1 = elist[i1];
      const int s1 = ei[e1];
      m1 = emc[e1];
      u1 = *(const float4*)(x  + (size_t)s1 * DIM + c4);
      w1 = *(const float4*)(ea + (size_t)e1 * DIM + c4);
    }
    const float mf = 1.f - m0;
    const float g0 = fmaxf(u0.x + w0.x, 0.f);
    const float g1 = fmaxf(u0.y + w0.y, 0.f);
    const float g2 = fmaxf(u0.z + w0.z, 0.f);
    const float g3 = fmaxf(u0.w + w0.w, 0.f);
    aC.x = fmaf(g0, m0, aC.x); aC.y = fmaf(g1, m0, aC.y);
    aC.z = fmaf(g2, m0, aC.z); aC.w = fmaf(g3, m0, aC.w);
    aF.x = fmaf(g0, mf, aF.x); aF.y = fmaf(g1, mf, aF.y);
    aF.z = fmaf(g2, mf, aF.z); aF.w = fmaf(g3, mf, aF.w);
    u0 = u1; w0 = w1; m0 = m1; i = i1; valid = v1;
  }
  // combine even/odd halves
  aC.x += __shfl_xor(aC.x, 32); aC.y += __shfl_xor(aC.y, 32);
  aC.z += __shfl_xor(aC.z, 32); aC.w += __shfl_xor(aC.w, 32);
  aF.x += __shfl_xor(aF.x, 32); aF.y += __shfl_xor(aF.y, 32);
  aF.z += __shfl_xor(aF.z, 32); aF.w += __shfl_xor(aF.w, 32);
  if (eh == 0) *(float4*)(aggrC + (size_t)n * DIM + c4) = aC;
  else         *(float4*)(aggrF + (size_t)n * DIM + c4) = aF;
}

// ---------------- BatchNorm stats (2-stage, deterministic) ----------------
__global__ __launch_bounds__(128) void bn_part_k(
    const float* X0, const float* X1, const float* X2, const float* X3,
    float* __restrict__ psum, float* __restrict__ psq)
{
  const int ti = blockIdx.y, chunk = blockIdx.x, col = threadIdx.x;
  const float* X = (ti == 0) ? X0 : (ti == 1) ? X1 : (ti == 2) ? X2 : X3;
  const float* p = X + (size_t)chunk * 256 * DIM + col;
  float s = 0.f, sq = 0.f;
  for (int r = 0; r < 256; r++) {
    const float xv = p[(size_t)r * DIM];
    s += xv; sq += xv * xv;
  }
  psum[(ti*32 + chunk)*DIM + col] = s;
  psq [(ti*32 + chunk)*DIM + col] = sq;
}

__global__ __launch_bounds__(128) void bn_final_k(
    const float* __restrict__ psum, const float* __restrict__ psq,
    const float* g0, const float* g1, const float* g2, const float* g3,
    const float* b0, const float* b1, const float* b2, const float* b3,
    float2* __restrict__ ss)
{
  const int ti = blockIdx.x, col = threadIdx.x;
  const float* g = (ti == 0) ? g0 : (ti == 1) ? g1 : (ti == 2) ? g2 : g3;
  const float* bb = (ti == 0) ? b0 : (ti == 1) ? b1 : (ti == 2) ? b2 : b3;
  float s = 0.f, sq = 0.f;
  for (int c = 0; c < 32; c++) { s += psum[(ti*32 + c)*DIM + col]; sq += psq[(ti*32 + c)*DIM + col]; }
  const float mean = s * (1.f/8192.f);
  const float var  = sq * (1.f/8192.f) - mean*mean;
  const float istd = rsqrtf(var + 1e-5f);
  const float scale = g[col] * istd;
  ss[ti*DIM + col] = make_float2(scale, bb[col] - mean*scale);
}

// ---------------- Final outputs ----------------
__global__ __launch_bounds__(256) void final_k(
    const float* __restrict__ fmc, const float* __restrict__ fmf,
    const float2* __restrict__ ssc, const float2* __restrict__ ssf,
    float* __restrict__ dout)
{
  const int idx4 = blockIdx.x * 256 + threadIdx.x;   // 0..262143
  const int base = idx4 * 4;
  const int col = base & 127;
  const float4 a = *(const float4*)(fmc + base);
  const float4 b = *(const float4*)(fmf + base);
  const float2 s0 = ssc[col], s1 = ssc[col+1], s2 = ssc[col+2], s3 = ssc[col+3];
  const float2 t0 = ssf[col], t1 = ssf[col+1], t2 = ssf[col+2], t3 = ssf[col+3];
  const float c0 = a.x*s0.x + s0.y, c1 = a.y*s1.x + s1.y, c2 = a.z*s2.x + s2.y, c3 = a.w*s3.x + s3.y;
  const float f0 = b.x*t0.x + t0.y, f1 = b.y*t1.x + t1.y, f2 = b.z*t2.x + t2.y, f3 = b.w*t3.x + t3.y;
  *(float4*)(dout + 1048576 + base) = make_float4(c0,c1,c2,c3);
  *(float4*)(dout + 2097152 + base) = make_float4(f0,f1,f2,f3);
  *(float4*)(dout + base) = make_float4(0.5f*(c0+f0), 0.5f*(c1+f1), 0.5f*(c2+f2), 0.5f*(c3+f3));
}

// ---------------- Launcher ----------------
extern "C" void kernel_launch(void* const* d_in, const int* in_sizes, int n_in,
                              void* d_out, int out_size, void* d_ws, size_t ws_size,
                              hipStream_t stream)
{
  const float* x    = (const float*)d_in[0];
  const int*   ei   = (const int*)  d_in[2];
  const float* ea   = (const float*)d_in[3];
  const float* temp = (const float*)d_in[4];
  const float* cenc = (const float*)d_in[5];
  const float* fenc = (const float*)d_in[6];
  const float* Wq   = (const float*)d_in[7];
  const float* bq_v = (const float*)d_in[8];
  const float* Wk   = (const float*)d_in[9];
  const float* bk_v = (const float*)d_in[10];
  const float* Wv   = (const float*)d_in[11];
  const float* bv_v = (const float*)d_in[12];
  const float* Wo   = (const float*)d_in[13];
  const float* bo_v = (const float*)d_in[14];
  const float* Wg1  = (const float*)d_in[15];
  const float* bg1v = (const float*)d_in[16];
  const float* Wg2  = (const float*)d_in[17];
  const float* bg2v = (const float*)d_in[18];
  const float* Wam  = (const float*)d_in[19];
  const float* bamv = (const float*)d_in[20];
  const float* Wm1  = (const float*)d_in[21];
  const float* bm1v = (const float*)d_in[22];
  const float* Wm2  = (const float*)d_in[23];
  const float* bm2v = (const float*)d_in[24];
  const float* g_attn  = (const float*)d_in[25];
  const float* be_attn = (const float*)d_in[26];
  const float* g_mpnn  = (const float*)d_in[27];
  const float* be_mpnn = (const float*)d_in[28];
  const float* g_mlp   = (const float*)d_in[29];
  const float* be_mlp  = (const float*)d_in[30];

  float* out = (float*)d_out;
  float* ws  = (float*)d_ws;
  const size_t M1 = 1048576;

  float* q    = ws + 0*M1;
  float* kbuf = ws + 1*M1;
  float* vbuf = ws + 2*M1;
  float* fcp  = ws + 3*M1;
  float* ffp  = ws + 4*M1;
  float* acr  = ws + 5*M1;
  float* afr  = ws + 6*M1;
  float* agc  = ws + 7*M1;
  float* agf  = ws + 8*M1;
  float* ghc  = ws + 9*M1;    // 2M (also CSR ints before GINE1 gemm)
  float* ghf  = ws + 11*M1;   // 2M
  float* emc  = ws + 13*M1;   // 262144
  float* psum = ws + 13*M1 + 262144;   // 16384
  float* psq  = psum + 16384;          // 16384
  float2* ss  = (float2*)(psq + 16384);
  // CSR scratch lives in the ghc region (free until GINE layer-1 gemm)
  int* cnt    = (int*)(ws + 9*M1);     // 8192
  int* off_a  = cnt + 8192;            // 8193
  int* cursor = off_a + 8200;          // 8192
  int* elist  = cursor + 8192;         // 262144
  // reuses (sequenced by stream order)
  float* mcr = q;
  float* mfr = kbuf;
  float* fC  = vbuf;
  float* fF  = fcp;
  float* fhc = ghc;
  float* fhf = ghf;
  float* fmc = ffp;
  float* fmf = agc;

  hipMemsetAsync(cnt, 0, 8192*sizeof(int), stream);

  const dim3 blk(256);

  // QKV projections
  {
    GemmJob jq{x, nullptr, nullptr, nullptr, Wq, bq_v, nullptr, q};
    GemmJob jk{x, nullptr, nullptr, nullptr, Wk, bk_v, nullptr, kbuf};
    GemmJob jv{x, nullptr, nullptr, nullptr, Wv, bv_v, nullptr, vbuf};
    gemm_k<0,0,0><<<dim3(2,64,3), blk, 0, stream>>>(jq, jk, jv, TTOK, 128, 128);
  }
  // Fused attention + entropy
  attn3_k<<<dim3(256), blk, 0, stream>>>(q, kbuf, vbuf, temp, fcp, ffp, out);
  // Edge sigmoid masks + dst histogram
  edge_k<<<dim3(8192), blk, 0, stream>>>(q, kbuf, ei, out + 3408384, emc, cnt);
  // CSR build
  scan_k<<<dim3(1), blk, 0, stream>>>(cnt, off_a, cursor);
  place_k<<<dim3(1024), blk, 0, stream>>>(ei, cursor, elist);
  // GINE gather aggregation (no atomics)
  gine_gather_k<<<dim3(2048), blk, 0, stream>>>(x, ea, ei, emc, off_a, elist, agc, agf);
  // Wo projection
  {
    GemmJob j0{fcp, nullptr, nullptr, nullptr, Wo, bo_v, nullptr, acr};
    GemmJob j1{ffp, nullptr, nullptr, nullptr, Wo, bo_v, nullptr, afr};
    gemm_k<0,0,0><<<dim3(2,64,2), blk, 0, stream>>>(j0, j1, j0, TTOK, 128, 128);
  }
  // GINE layer 1 (h = x + aggr, relu)
  {
    GemmJob j0{x, agc, nullptr, nullptr, Wg1, bg1v, nullptr, ghc};
    GemmJob j1{x, agf, nullptr, nullptr, Wg1, bg1v, nullptr, ghf};
    gemm_k<1,1,0><<<dim3(4,64,2), blk, 0, stream>>>(j0, j1, j0, TTOK, 256, 128);
  }
  // GINE layer 2
  {
    GemmJob j0{ghc, nullptr, nullptr, nullptr, Wg2, bg2v, nullptr, mcr};
    GemmJob j1{ghf, nullptr, nullptr, nullptr, Wg2, bg2v, nullptr, mfr};
    gemm_k<0,0,0><<<dim3(2,64,2), blk, 0, stream>>>(j0, j1, j0, TTOK, 128, 256);
  }
  // BN stats round 1: acr, afr, mcr, mfr
  bn_part_k<<<dim3(32,4), dim3(128), 0, stream>>>(acr, afr, mcr, mfr, psum, psq);
  bn_final_k<<<dim3(4), dim3(128), 0, stream>>>(psum, psq,
      g_attn, g_attn, g_mpnn, g_mpnn, be_attn, be_attn, be_mpnn, be_mpnn, ss);
  // Fuse linear: concat(bn(attn), bn(mpnn)) @ Wam + bam
  {
    GemmJob j0{acr, mcr, ss + 0,   ss + 256, Wam, bamv, nullptr, fC};
    GemmJob j1{afr, mfr, ss + 128, ss + 384, Wam, bamv, nullptr, fF};
    gemm_k<2,0,0><<<dim3(2,64,2), blk, 0, stream>>>(j0, j1, j0, TTOK, 128, 256);
  }
  // Fuse MLP layer 1 (relu)
  {
    GemmJob j0{fC, nullptr, nullptr, nullptr, Wm1, bm1v, nullptr, fhc};
    GemmJob j1{fF, nullptr, nullptr, nullptr, Wm1, bm1v, nullptr, fhf};
    gemm_k<0,1,0><<<dim3(4,64,2), blk, 0, stream>>>(j0, j1, j0, TTOK, 256, 128);
  }
  // Fuse MLP layer 2 + residual f
  {
    GemmJob j0{fhc, nullptr, nullptr, nullptr, Wm2, bm2v, fC, fmc};
    GemmJob j1{fhf, nullptr, nullptr, nullptr, Wm2, bm2v, fF, fmf};
    gemm_k<0,0,1><<<dim3(2,64,2), blk, 0, stream>>>(j0, j1, j0, TTOK, 128, 256);
  }
  // BN stats round 2: fmc, fmf
  bn_part_k<<<dim3(32,2), dim3(128), 0, stream>>>(fmc, fmf, fmc, fmc, psum, psq);
  bn_final_k<<<dim3(2), dim3(128), 0, stream>>>(psum, psq,
      g_mlp, g_mlp, g_mlp, g_mlp, be_mlp, be_mlp, be_mlp, be_mlp, ss + 512);
  // Final features + new_x
  final_k<<<dim3(1024), blk, 0, stream>>>(fmc, fmf, ss + 512, ss + 640, out);
  // Pass-through encodings
  hipMemcpyAsync(out + 3146240, (const void*)cenc, 131072*sizeof(float),
                 hipMemcpyDeviceToDevice, stream);
  hipMemcpyAsync(out + 3277312, (const void*)fenc, 131072*sizeof(float),
                 hipMemcpyDeviceToDevice, stream);
}

// Round 5
// 324.544 us; speedup vs baseline: 1.0314x; 1.0314x over previous
//
#include <hip/hip_runtime.h>

#define TTOK   8192
#define BGR    32
#define NNODE  256
#define DIM    128
#define NH     8
#define HD     16
#define NEDGE  262144
#define SCALE_QK 0.25f

typedef short bf16x8 __attribute__((ext_vector_type(8)));
typedef float f32x4  __attribute__((ext_vector_type(4)));

__device__ __forceinline__ ushort bf_hi(float x, float &rem) {
  unsigned u = __float_as_uint(x) & 0xffff0000u;
  rem = x - __uint_as_float(u);
  return (ushort)(u >> 16);
}
__device__ __forceinline__ ushort bf_rne(float x) {
  unsigned u = __float_as_uint(x);
  u += 0x7fffu + ((u >> 16) & 1u);
  return (ushort)(u >> 16);
}

// ---------------- Weight prep: f32 -> (hi,lo) bf16 in MFMA fragment order ----------------
// frag idx for W[K][N]: ((n/16)*(K/8) + k/8)*128 + (n%16)*8 + (k%8)
struct WArg { const float* w[8]; int K[8]; int nlog[8]; int off[8]; };

__global__ __launch_bounds__(256) void wprep_k(WArg a, ushort* out) {
  const int m = blockIdx.y;
  const int K = a.K[m];
  const int nl = a.nlog[m];
  const int sz = K << nl;
  const int e = blockIdx.x * 256 + threadIdx.x;
  if (e >= sz) return;
  const int k = e >> nl, n = e & ((1 << nl) - 1);
  const float x = a.w[m][e];
  float r;
  const ushort h = bf_hi(x, r);
  const ushort l = bf_rne(r);
  const int idx = (((n >> 4) * (K >> 3) + (k >> 3)) << 7) + ((n & 15) << 3) + (k & 7);
  out[a.off[m] + idx] = h;
  out[a.off[m] + sz + idx] = l;
}

// ---------------- Wam prep: fold BN scale/shift into weights+bias ----------------
__global__ __launch_bounds__(128) void wam_prep_k(
    const float* __restrict__ Wam, const float* __restrict__ bam,
    const float2* __restrict__ ssAll, ushort* __restrict__ outbase,
    float* __restrict__ biasC, float* __restrict__ biasF)
{
  const int br = blockIdx.x;                 // 0 = causal, 1 = conf
  const float2* s1 = ssAll + (br ? 128 : 0);
  const float2* s2 = ssAll + (br ? 384 : 256);
  ushort* oh = outbase + 393216 + br * 65536;
  ushort* ol = oh + 32768;
  float* bout = br ? biasF : biasC;
  const int n = threadIdx.x;
  float tacc = 0.f;
  for (int k = 0; k < 256; k++) {
    const float2 st = (k < 128) ? s1[k] : s2[k - 128];
    const float w = Wam[k * 128 + n];
    tacc = fmaf(st.y, w, tacc);
    const float wp = st.x * w;
    float r;
    const ushort h = bf_hi(wp, r);
    const ushort l = bf_rne(r);
    const int idx = (((n >> 4) * 32 + (k >> 3)) << 7) + ((n & 15) << 3) + (k & 7);
    oh[idx] = h; ol[idx] = l;
  }
  bout[n] = bam[n] + tacc;
}

// ---------------- MFMA GEMM (bf16x3 split, no LDS, no barriers) ----------------
struct MJob {
  const float*  A1;
  const float*  A2;
  const ushort* Wh;
  const ushort* Wl;
  const float*  bias;
  const float*  res;
  float*        C;
};

// BM=64, BN=128; 256 thr = 4 waves (2x2); wave = 32 rows x 64 cols (TR=2, TC=4).
// AMODE: 0 = A1 (lda=K); 1 = A1+A2 (lda=128); 2 = concat(A1,A2) (lda=128 each, K=256)
template<int AMODE, int RELU, int HASRES, int K>
__global__ __launch_bounds__(256) void gemm_mfma_k(MJob j0, MJob j1, MJob j2, int N)
{
  const MJob jb = (blockIdx.z == 0) ? j0 : ((blockIdx.z == 1) ? j1 : j2);
  const int tid = threadIdx.x;
  const int w = tid >> 6, lane = tid & 63;
  const int wr = w >> 1, wc = w & 1;
  const int lr = lane & 15, lk = lane >> 4;
  const int bm = blockIdx.y * 64;
  const int bn = blockIdx.x * 128;
  const int row0 = bm + wr * 32 + lr;
  constexpr int K8 = K / 8;
  f32x4 acc[2][4] = {};

  #pragma unroll
  for (int ks = 0; ks < K / 32; ks++) {
    // A fragments (direct global f32 -> hi/lo bf16)
    bf16x8 ah[2], al[2];
    #pragma unroll
    for (int rt = 0; rt < 2; rt++) {
      const int row = row0 + rt * 16;
      float av[8];
      if (AMODE == 0) {
        const float* p = jb.A1 + (size_t)row * K + ks * 32 + lk * 8;
        const f32x4 u0 = *(const f32x4*)p;
        const f32x4 u1 = *(const f32x4*)(p + 4);
        av[0]=u0[0]; av[1]=u0[1]; av[2]=u0[2]; av[3]=u0[3];
        av[4]=u1[0]; av[5]=u1[1]; av[6]=u1[2]; av[7]=u1[3];
      } else if (AMODE == 1) {
        const float* p = jb.A1 + (size_t)row * 128 + ks * 32 + lk * 8;
        const float* q = jb.A2 + (size_t)row * 128 + ks * 32 + lk * 8;
        const f32x4 u0 = *(const f32x4*)p;
        const f32x4 u1 = *(const f32x4*)(p + 4);
        const f32x4 v0 = *(const f32x4*)q;
        const f32x4 v1 = *(const f32x4*)(q + 4);
        av[0]=u0[0]+v0[0]; av[1]=u0[1]+v0[1]; av[2]=u0[2]+v0[2]; av[3]=u0[3]+v0[3];
        av[4]=u1[0]+v1[0]; av[5]=u1[1]+v1[1]; av[6]=u1[2]+v1[2]; av[7]=u1[3]+v1[3];
      } else {
        const float* p = (ks * 32 < 128)
          ? jb.A1 + (size_t)row * 128 + ks * 32 + lk * 8
          : jb.A2 + (size_t)row * 128 + (ks * 32 - 128) + lk * 8;
        const f32x4 u0 = *(const f32x4*)p;
        const f32x4 u1 = *(const f32x4*)(p + 4);
        av[0]=u0[0]; av[1]=u0[1]; av[2]=u0[2]; av[3]=u0[3];
        av[4]=u1[0]; av[5]=u1[1]; av[6]=u1[2]; av[7]=u1[3];
      }
      #pragma unroll
      for (int i = 0; i < 8; i++) {
        float r;
        ah[rt][i] = (short)bf_hi(av[i], r);
        al[rt][i] = (short)bf_rne(r);
      }
    }
    // B fragments (pre-layouted) + MFMA
    #pragma unroll
    for (int ct = 0; ct < 4; ct++) {
      const int ntile = (bn >> 4) + wc * 4 + ct;
      const size_t foff = (((size_t)ntile * K8 + ks * 4 + lk) << 7) + ((size_t)lr << 3);
      const bf16x8 bh = *(const bf16x8*)(jb.Wh + foff);
      const bf16x8 bl = *(const bf16x8*)(jb.Wl + foff);
      #pragma unroll
      for (int rt = 0; rt < 2; rt++) {
        acc[rt][ct] = __builtin_amdgcn_mfma_f32_16x16x32_bf16(ah[rt], bh, acc[rt][ct], 0, 0, 0);
        acc[rt][ct] = __builtin_amdgcn_mfma_f32_16x16x32_bf16(al[rt], bh, acc[rt][ct], 0, 0, 0);
        acc[rt][ct] = __builtin_amdgcn_mfma_f32_16x16x32_bf16(ah[rt], bl, acc[rt][ct], 0, 0, 0);
      }
    }
  }

  // epilogue: C row = (lane>>4)*4 + reg, col = lane&15
  #pragma unroll
  for (int ct = 0; ct < 4; ct++) {
    const int col = bn + wc * 64 + ct * 16 + lr;
    const float bb = jb.bias[col];
    #pragma unroll
    for (int rt = 0; rt < 2; rt++) {
      #pragma unroll
      for (int r = 0; r < 4; r++) {
        const int row = bm + wr * 32 + rt * 16 + lk * 4 + r;
        float o = acc[rt][ct][r] + bb;
        if (RELU) o = fmaxf(o, 0.f);
        if (HASRES) o += jb.res[(size_t)row * N + col];
        jb.C[(size_t)row * N + col] = o;
      }
    }
  }
}

// ---------------- Fused attention v3: thread-pair per 2 rows, j-parity split ----------------
__global__ __launch_bounds__(256) void attn3_k(
    const float* __restrict__ q, const float* __restrict__ k, const float* __restrict__ v,
    const float* __restrict__ tptr, float* __restrict__ fc, float* __restrict__ ff,
    float* __restrict__ dout)
{
  const int bh = blockIdx.x;
  const int b = bh >> 3, h = bh & 7;
  __shared__ float Ks[256][16];
  __shared__ float Vs[256][16];
  __shared__ float red[4][2];
  const int tid = threadIdx.x;
  {
    const float* kr = k + ((size_t)(b*NNODE + tid))*DIM + h*HD;
    const float* vr = v + ((size_t)(b*NNODE + tid))*DIM + h*HD;
    #pragma unroll
    for (int p = 0; p < 4; p++) {
      *(float4*)&Ks[tid][4*p] = *(const float4*)(kr + 4*p);
      *(float4*)&Vs[tid][4*p] = *(const float4*)(vr + 4*p);
    }
  }
  const int pr  = tid >> 1;
  const int par = tid & 1;
  const int r0 = pr * 2;
  const float sc = SCALE_QK / tptr[0];
  float qa[16], qb[16];
  {
    const float* qr = q + ((size_t)(b*NNODE + r0))*DIM + h*HD;
    #pragma unroll
    for (int p = 0; p < 4; p++) {
      float4 a = *(const float4*)(qr + 4*p);
      qa[4*p+0]=a.x*sc; qa[4*p+1]=a.y*sc; qa[4*p+2]=a.z*sc; qa[4*p+3]=a.w*sc;
      float4 c = *(const float4*)(qr + DIM + 4*p);
      qb[4*p+0]=c.x*sc; qb[4*p+1]=c.y*sc; qb[4*p+2]=c.z*sc; qb[4*p+3]=c.w*sc;
    }
  }
  __syncthreads();

  float mxa=-1e30f, mna=1e30f, mxb=-1e30f, mnb=1e30f;
  for (int j = par; j < NNODE; j += 2) {
    const float4 k0 = *(const float4*)&Ks[j][0];
    const float4 k1 = *(const float4*)&Ks[j][4];
    const float4 k2 = *(const float4*)&Ks[j][8];
    const float4 k3 = *(const float4*)&Ks[j][12];
    float sa = qa[0]*k0.x; float sb = qb[0]*k0.x;
    sa = fmaf(qa[1],k0.y,sa); sb = fmaf(qb[1],k0.y,sb);
    sa = fmaf(qa[2],k0.z,sa); sb = fmaf(qb[2],k0.z,sb);
    sa = fmaf(qa[3],k0.w,sa); sb = fmaf(qb[3],k0.w,sb);
    sa = fmaf(qa[4],k1.x,sa); sb = fmaf(qb[4],k1.x,sb);
    sa = fmaf(qa[5],k1.y,sa); sb = fmaf(qb[5],k1.y,sb);
    sa = fmaf(qa[6],k1.z,sa); sb = fmaf(qb[6],k1.z,sb);
    sa = fmaf(qa[7],k1.w,sa); sb = fmaf(qb[7],k1.w,sb);
    sa = fmaf(qa[8],k2.x,sa); sb = fmaf(qb[8],k2.x,sb);
    sa = fmaf(qa[9],k2.y,sa); sb = fmaf(qb[9],k2.y,sb);
    sa = fmaf(qa[10],k2.z,sa); sb = fmaf(qb[10],k2.z,sb);
    sa = fmaf(qa[11],k2.w,sa); sb = fmaf(qb[11],k2.w,sb);
    sa = fmaf(qa[12],k3.x,sa); sb = fmaf(qb[12],k3.x,sb);
    sa = fmaf(qa[13],k3.y,sa); sb = fmaf(qb[13],k3.y,sb);
    sa = fmaf(qa[14],k3.z,sa); sb = fmaf(qb[14],k3.z,sb);
    sa = fmaf(qa[15],k3.w,sa); sb = fmaf(qb[15],k3.w,sb);
    mxa = fmaxf(mxa, sa); mna = fminf(mna, sa);
    mxb = fmaxf(mxb, sb); mnb = fminf(mnb, sb);
  }
  mxa = fmaxf(mxa, __shfl_xor(mxa, 1)); mna = fminf(mna, __shfl_xor(mna, 1));
  mxb = fmaxf(mxb, __shfl_xor(mxb, 1)); mnb = fminf(mnb, __shfl_xor(mnb, 1));

  float zca=0,zfa=0,Eca=0,Efa=0, zcb=0,zfb=0,Ecb=0,Efb=0;
  float oca[16], ofa[16], ocb[16], ofb[16];
  #pragma unroll
  for (int d = 0; d < 16; d++) { oca[d]=0.f; ofa[d]=0.f; ocb[d]=0.f; ofb[d]=0.f; }
  for (int j = par; j < NNODE; j += 2) {
    const float4 k0 = *(const float4*)&Ks[j][0];
    const float4 k1 = *(const float4*)&Ks[j][4];
    const float4 k2 = *(const float4*)&Ks[j][8];
    const float4 k3 = *(const float4*)&Ks[j][12];
    float sa = qa[0]*k0.x; float sb = qb[0]*k0.x;
    sa = fmaf(qa[1],k0.y,sa); sb = fmaf(qb[1],k0.y,sb);
    sa = fmaf(qa[2],k0.z,sa); sb = fmaf(qb[2],k0.z,sb);
    sa = fmaf(qa[3],k0.w,sa); sb = fmaf(qb[3],k0.w,sb);
    sa = fmaf(qa[4],k1.x,sa); sb = fmaf(qb[4],k1.x,sb);
    sa = fmaf(qa[5],k1.y,sa); sb = fmaf(qb[5],k1.y,sb);
    sa = fmaf(qa[6],k1.z,sa); sb = fmaf(qb[6],k1.z,sb);
    sa = fmaf(qa[7],k1.w,sa); sb = fmaf(qb[7],k1.w,sb);
    sa = fmaf(qa[8],k2.x,sa); sb = fmaf(qb[8],k2.x,sb);
    sa = fmaf(qa[9],k2.y,sa); sb = fmaf(qb[9],k2.y,sb);
    sa = fmaf(qa[10],k2.z,sa); sb = fmaf(qb[10],k2.z,sb);
    sa = fmaf(qa[11],k2.w,sa); sb = fmaf(qb[11],k2.w,sb);
    sa = fmaf(qa[12],k3.x,sa); sb = fmaf(qb[12],k3.x,sb);
    sa = fmaf(qa[13],k3.y,sa); sb = fmaf(qb[13],k3.y,sb);
    sa = fmaf(qa[14],k3.z,sa); sb = fmaf(qb[14],k3.z,sb);
    sa = fmaf(qa[15],k3.w,sa); sb = fmaf(qb[15],k3.w,sb);
    const float eca = __expf(sa - mxa);
    const float efa = __expf(mna - sa);
    const float ecb = __expf(sb - mxb);
    const float efb = __expf(mnb - sb);
    zca += eca; zfa += efa; zcb += ecb; zfb += efb;
    Eca = fmaf(eca, sa, Eca); Efa = fmaf(efa, -sa, Efa);
    Ecb = fmaf(ecb, sb, Ecb); Efb = fmaf(efb, -sb, Efb);
    const float4 v0 = *(const float4*)&Vs[j][0];
    const float4 v1 = *(const float4*)&Vs[j][4];
    const float4 v2 = *(const float4*)&Vs[j][8];
    const float4 v3 = *(const float4*)&Vs[j][12];
    const float vv[16] = {v0.x,v0.y,v0.z,v0.w, v1.x,v1.y,v1.z,v1.w,
                          v2.x,v2.y,v2.z,v2.w, v3.x,v3.y,v3.z,v3.w};
    #pragma unroll
    for (int d = 0; d < 16; d++) {
      oca[d] = fmaf(eca, vv[d], oca[d]);
      ofa[d] = fmaf(efa, vv[d], ofa[d]);
      ocb[d] = fmaf(ecb, vv[d], ocb[d]);
      ofb[d] = fmaf(efb, vv[d], ofb[d]);
    }
  }
  zca += __shfl_xor(zca, 1); zfa += __shfl_xor(zfa, 1);
  zcb += __shfl_xor(zcb, 1); zfb += __shfl_xor(zfb, 1);
  Eca += __shfl_xor(Eca, 1); Efa += __shfl_xor(Efa, 1);
  Ecb += __shfl_xor(Ecb, 1); Efb += __shfl_xor(Efb, 1);
  #pragma unroll
  for (int d = 0; d < 16; d++) {
    oca[d] += __shfl_xor(oca[d], 1);
    ofa[d] += __shfl_xor(ofa[d], 1);
    ocb[d] += __shfl_xor(ocb[d], 1);
    ofb[d] += __shfl_xor(ofb[d], 1);
  }
  float entc = 0.f, entf = 0.f;
  if (par == 0) {
    const float rca = 1.f/zca, rfa = 1.f/zfa, rcb = 1.f/zcb, rfb = 1.f/zfb;
    entc = (mxa + __logf(zca) - Eca*rca) + (mxb + __logf(zcb) - Ecb*rcb);
    entf = (-mna + __logf(zfa) - Efa*rfa) + (-mnb + __logf(zfb) - Efb*rfb);
    float* pc = fc + ((size_t)(b*NNODE + r0))*DIM + h*HD;
    float* pf = ff + ((size_t)(b*NNODE + r0))*DIM + h*HD;
    #pragma unroll
    for (int p = 0; p < 4; p++) {
      *(float4*)(pc + 4*p)       = make_float4(oca[4*p]*rca, oca[4*p+1]*rca, oca[4*p+2]*rca, oca[4*p+3]*rca);
      *(float4*)(pc + DIM + 4*p) = make_float4(ocb[4*p]*rcb, ocb[4*p+1]*rcb, ocb[4*p+2]*rcb, ocb[4*p+3]*rcb);
      *(float4*)(pf + 4*p)       = make_float4(ofa[4*p]*rfa, ofa[4*p+1]*rfa, ofa[4*p+2]*rfa, ofa[4*p+3]*rfa);
      *(float4*)(pf + DIM + 4*p) = make_float4(ofb[4*p]*rfb, ofb[4*p+1]*rfb, ofb[4*p+2]*rfb, ofb[4*p+3]*rfb);
    }
  }
  #pragma unroll
  for (int off = 1; off < 64; off <<= 1) {
    entc += __shfl_xor(entc, off);
    entf += __shfl_xor(entf, off);
  }
  const int wv = tid >> 6;
  if ((tid & 63) == 0) { red[wv][0] = entc; red[wv][1] = entf; }
  __syncthreads();
  if (tid == 0) {
    const float tc = red[0][0]+red[1][0]+red[2][0]+red[3][0];
    const float tf = red[0][1]+red[1][1]+red[2][1]+red[3][1];
    dout[3145728 + bh] = tc * (1.0f/256.0f);
    dout[3145984 + bh] = tf * (1.0f/256.0f);
  }
}

// ---------------- Edge sigmoid mask + dst histogram ----------------
__global__ __launch_bounds__(256) void edge_k(
    const float* __restrict__ q, const float* __restrict__ k,
    const int* __restrict__ ei, float* __restrict__ maskout, float* __restrict__ emc,
    int* __restrict__ cnt)
{
  const int gt = blockIdx.x * 256 + threadIdx.x;
  const int e = gt >> 3, h = gt & 7;
  const int src = ei[e];
  const int dst = ei[NEDGE + e];
  const float* qr = q + (size_t)src * DIM + h*HD;
  const float* kr = k + (size_t)dst * DIM + h*HD;
  float s = 0.f;
  #pragma unroll
  for (int p = 0; p < 4; p++) {
    float4 a = *(const float4*)(qr + 4*p);
    float4 c = *(const float4*)(kr + 4*p);
    s += a.x*c.x + a.y*c.y + a.z*c.z + a.w*c.w;
  }
  s *= SCALE_QK;
  const float sig = 1.f / (1.f + __expf(-s));
  maskout[gt] = sig;
  float m = sig;
  m += __shfl_xor(m, 1); m += __shfl_xor(m, 2); m += __shfl_xor(m, 4);
  if ((threadIdx.x & 7) == 0) {
    emc[e] = m * 0.125f;
    atomicAdd(&cnt[dst], 1);
  }
}

// ---------------- CSR build ----------------
__global__ __launch_bounds__(256) void scan_k(const int* __restrict__ cnt,
                                              int* __restrict__ off,
                                              int* __restrict__ cursor)
{
  __shared__ int part[256];
  const int t = threadIdx.x;
  const int base = t * 32;
  int local[32];
  int s = 0;
  #pragma unroll
  for (int i = 0; i < 32; i++) { local[i] = s; s += cnt[base + i]; }
  part[t] = s;
  __syncthreads();
  int pre = 0;
  for (int i = 0; i < t; i++) pre += part[i];
  #pragma unroll
  for (int i = 0; i < 32; i++) {
    const int v = pre + local[i];
    off[base + i] = v;
    cursor[base + i] = v;
  }
  if (t == 255) off[8192] = pre + s;
}

__global__ __launch_bounds__(256) void place_k(const int* __restrict__ ei,
                                               int* __restrict__ cursor,
                                               int* __restrict__ elist)
{
  const int e = blockIdx.x * 256 + threadIdx.x;
  const int d = ei[NEDGE + e];
  const int pos = atomicAdd(&cursor[d], 1);
  elist[pos] = e;
}

// ---------------- GINE gather-aggregate (one wave per node) ----------------
__global__ __launch_bounds__(256) void gine_gather_k(
    const float* __restrict__ x, const float* __restrict__ ea,
    const int* __restrict__ ei, const float* __restrict__ emc,
    const int* __restrict__ off, const int* __restrict__ elist,
    float* __restrict__ aggrC, float* __restrict__ aggrF)
{
  const int wv = threadIdx.x >> 6, lane = threadIdx.x & 63;
  const int eh = lane >> 5;
  const int c4 = (lane & 31) * 4;
  const int n = blockIdx.x * 4 + wv;
  float4 aC = make_float4(0,0,0,0), aF = make_float4(0,0,0,0);
  int i = off[n] + eh;
  const int end = off[n + 1];
  bool valid = i < end;
  int e0 = 0, s0 = 0; float m0 = 0.f;
  float4 u0 = make_float4(0,0,0,0), w0 = make_float4(0,0,0,0);
  if (valid) {
    e0 = elist[i]; s0 = ei[e0]; m0 = emc[e0];
    u0 = *(const float4*)(x  + (size_t)s0 * DIM + c4);
    w0 = *(const float4*)(ea + (size_t)e0 * DIM + c4);
  }
  while (valid) {
    const int i1 = i + 2;
    const bool v1 = i1 < end;
    float4 u1 = make_float4(0,0,0,0), w1 = make_float4(0,0,0,0);
    float m1 = 0.f;
    if (v1) {
      const int e1 = elist[i1];
      const int s1 = ei[e1];
      m1 = emc[e1];
      u1 = *(const float4*)(x  + (size_t)s1 * DIM + c4);
      w1 = *(const float4*)(ea + (size_t)e1 * DIM + c4);
    }
    const float mf = 1.f - m0;
    const float g0 = fmaxf(u0.x + w0.x, 0.f);
    const float g1 = fmaxf(u0.y + w0.y, 0.f);
    const float g2 = fmaxf(u0.z + w0.z, 0.f);
    const float g3 = fmaxf(u0.w + w0.w, 0.f);
    aC.x = fmaf(g0, m0, aC.x); aC.y = fmaf(g1, m0, aC.y);
    aC.z = fmaf(g2, m0, aC.z); aC.w = fmaf(g3, m0, aC.w);
    aF.x = fmaf(g0, mf, aF.x); aF.y = fmaf(g1, mf, aF.y);
    aF.z = fmaf(g2, mf, aF.z); aF.w = fmaf(g3, mf, aF.w);
    u0 = u1; w0 = w1; m0 = m1; i = i1; valid = v1;
  }
  aC.x += __shfl_xor(aC.x, 32); aC.y += __shfl_xor(aC.y, 32);
  aC.z += __shfl_xor(aC.z, 32); aC.w += __shfl_xor(aC.w, 32);
  aF.x += __shfl_xor(aF.x, 32); aF.y += __shfl_xor(aF.y, 32);
  aF.z += __shfl_xor(aF.z, 32); aF.w += __shfl_xor(aF.w, 32);
  if (eh == 0) *(float4*)(aggrC + (size_t)n * DIM + c4) = aC;
  else         *(float4*)(aggrF + (size_t)n * DIM + c4) = aF;
}

// ---------------- BatchNorm stats ----------------
__global__ __launch_bounds__(128) void bn_part_k(
    const float* X0, const float* X1, const float* X2, const float* X3,
    float* __restrict__ psum, float* __restrict__ psq)
{
  const int ti = blockIdx.y, chunk = blockIdx.x, col = threadIdx.x;
  const float* X = (ti == 0) ? X0 : (ti == 1) ? X1 : (ti == 2) ? X2 : X3;
  const float* p = X + (size_t)chunk * 256 * DIM + col;
  float s = 0.f, sq = 0.f;
  for (int r = 0; r < 256; r++) {
    const float xv = p[(size_t)r * DIM];
    s += xv; sq += xv * xv;
  }
  psum[(ti*32 + chunk)*DIM + col] = s;
  psq [(ti*32 + chunk)*DIM + col] = sq;
}

__global__ __launch_bounds__(128) void bn_final_k(
    const float* __restrict__ psum, const float* __restrict__ psq,
    const float* g0, const float* g1, const float* g2, const float* g3,
    const float* b0, const float* b1, const float* b2, const float* b3,
    float2* __restrict__ ss)
{
  const int ti = blockIdx.x, col = threadIdx.x;
  const float* g = (ti == 0) ? g0 : (ti == 1) ? g1 : (ti == 2) ? g2 : g3;
  const float* bb = (ti == 0) ? b0 : (ti == 1) ? b1 : (ti == 2) ? b2 : b3;
  float s = 0.f, sq = 0.f;
  for (int c = 0; c < 32; c++) { s += psum[(ti*32 + c)*DIM + col]; sq += psq[(ti*32 + c)*DIM + col]; }
  const float mean = s * (1.f/8192.f);
  const float var  = sq * (1.f/8192.f) - mean*mean;
  const float istd = rsqrtf(var + 1e-5f);
  const float scale = g[col] * istd;
  ss[ti*DIM + col] = make_float2(scale, bb[col] - mean*scale);
}

// ---------------- Final outputs ----------------
__global__ __launch_bounds__(256) void final_k(
    const float* __restrict__ fmc, const float* __restrict__ fmf,
    const float2* __restrict__ ssc, const float2* __restrict__ ssf,
    float* __restrict__ dout)
{
  const int idx4 = blockIdx.x * 256 + threadIdx.x;
  const int base = idx4 * 4;
  const int col = base & 127;
  const float4 a = *(const float4*)(fmc + base);
  const float4 b = *(const float4*)(fmf + base);
  const float2 s0 = ssc[col], s1 = ssc[col+1], s2 = ssc[col+2], s3 = ssc[col+3];
  const float2 t0 = ssf[col], t1 = ssf[col+1], t2 = ssf[col+2], t3 = ssf[col+3];
  const float c0 = a.x*s0.x + s0.y, c1 = a.y*s1.x + s1.y, c2 = a.z*s2.x + s2.y, c3 = a.w*s3.x + s3.y;
  const float f0 = b.x*t0.x + t0.y, f1 = b.y*t1.x + t1.y, f2 = b.z*t2.x + t2.y, f3 = b.w*t3.x + t3.y;
  *(float4*)(dout + 1048576 + base) = make_float4(c0,c1,c2,c3);
  *(float4*)(dout + 2097152 + base) = make_float4(f0,f1,f2,f3);
  *(float4*)(dout + base) = make_float4(0.5f*(c0+f0), 0.5f*(c1+f1), 0.5f*(c2+f2), 0.5f*(c3+f3));
}

// ---------------- Launcher ----------------
extern "C" void kernel_launch(void* const* d_in, const int* in_sizes, int n_in,
                              void* d_out, int out_size, void* d_ws, size_t ws_size,
                              hipStream_t stream)
{
  const float* x    = (const float*)d_in[0];
  const int*   ei   = (const int*)  d_in[2];
  const float* ea   = (const float*)d_in[3];
  const float* temp = (const float*)d_in[4];
  const float* cenc = (const float*)d_in[5];
  const float* fenc = (const float*)d_in[6];
  const float* Wq   = (const float*)d_in[7];
  const float* bq_v = (const float*)d_in[8];
  const float* Wk   = (const float*)d_in[9];
  const float* bk_v = (const float*)d_in[10];
  const float* Wv   = (const float*)d_in[11];
  const float* bv_v = (const float*)d_in[12];
  const float* Wo   = (const float*)d_in[13];
  const float* bo_v = (const float*)d_in[14];
  const float* Wg1  = (const float*)d_in[15];
  const float* bg1v = (const float*)d_in[16];
  const float* Wg2  = (const float*)d_in[17];
  const float* bg2v = (const float*)d_in[18];
  const float* Wam  = (const float*)d_in[19];
  const float* bamv = (const float*)d_in[20];
  const float* Wm1  = (const float*)d_in[21];
  const float* bm1v = (const float*)d_in[22];
  const float* Wm2  = (const float*)d_in[23];
  const float* bm2v = (const float*)d_in[24];
  const float* g_attn  = (const float*)d_in[25];
  const float* be_attn = (const float*)d_in[26];
  const float* g_mpnn  = (const float*)d_in[27];
  const float* be_mpnn = (const float*)d_in[28];
  const float* g_mlp   = (const float*)d_in[29];
  const float* be_mlp  = (const float*)d_in[30];

  float* out = (float*)d_out;
  float* ws  = (float*)d_ws;
  const size_t M1 = 1048576;

  float* q    = ws + 0*M1;
  float* kbuf = ws + 1*M1;
  float* vbuf = ws + 2*M1;
  float* fcp  = ws + 3*M1;
  float* ffp  = ws + 4*M1;
  float* acr  = ws + 5*M1;
  float* afr  = ws + 6*M1;
  float* agc  = ws + 7*M1;
  float* agf  = ws + 8*M1;
  float* ghc  = ws + 9*M1;    // 2M (also CSR ints before GINE1 gemm)
  float* ghf  = ws + 11*M1;   // 2M
  float* emc  = ws + 13*M1;            // 262144
  float* psum = emc + 262144;          // 16384
  float* psq  = psum + 16384;          // 16384
  float2* ss  = (float2*)(psq + 16384);   // 768 float2
  float* biasC = (float*)(ss + 768);      // 128
  float* biasF = biasC + 128;             // 128
  ushort* wfr = (ushort*)(ws + 14*M1);    // 524288 ushorts (1MB)
  // CSR scratch in ghc region (free until GINE layer-1 gemm)
  int* cnt    = (int*)(ws + 9*M1);
  int* off_a  = cnt + 8192;
  int* cursor = off_a + 8200;
  int* elist  = cursor + 8192;
  // reuses (sequenced by stream order)
  float* mcr = q;
  float* mfr = kbuf;
  float* fC  = vbuf;
  float* fF  = fcp;
  float* fhc = ghc;
  float* fhf = ghf;
  float* fmc = ffp;
  float* fmf = agc;

  // weight frag offsets (ushorts): [hi | lo] per matrix
  const int OWq = 0, OWk = 32768, OWv = 65536, OWo = 98304;
  const int OWg1 = 131072, OWg2 = 196608, OWm1 = 262144, OWm2 = 327680;
  const int OWamC = 393216, OWamF = 458752;

  hipMemsetAsync(cnt, 0, 8192*sizeof(int), stream);

  const dim3 blk(256);

  // Weight prep (all except Wam)
  {
    WArg a;
    a.w[0]=Wq;  a.K[0]=128; a.nlog[0]=7; a.off[0]=OWq;
    a.w[1]=Wk;  a.K[1]=128; a.nlog[1]=7; a.off[1]=OWk;
    a.w[2]=Wv;  a.K[2]=128; a.nlog[2]=7; a.off[2]=OWv;
    a.w[3]=Wo;  a.K[3]=128; a.nlog[3]=7; a.off[3]=OWo;
    a.w[4]=Wg1; a.K[4]=128; a.nlog[4]=8; a.off[4]=OWg1;
    a.w[5]=Wg2; a.K[5]=256; a.nlog[5]=7; a.off[5]=OWg2;
    a.w[6]=Wm1; a.K[6]=128; a.nlog[6]=8; a.off[6]=OWm1;
    a.w[7]=Wm2; a.K[7]=256; a.nlog[7]=7; a.off[7]=OWm2;
    wprep_k<<<dim3(128, 8), blk, 0, stream>>>(a, wfr);
  }
  // QKV projections
  {
    MJob jq{x, nullptr, wfr+OWq, wfr+OWq+16384, bq_v, nullptr, q};
    MJob jk{x, nullptr, wfr+OWk, wfr+OWk+16384, bk_v, nullptr, kbuf};
    MJob jv{x, nullptr, wfr+OWv, wfr+OWv+16384, bv_v, nullptr, vbuf};
    gemm_mfma_k<0,0,0,128><<<dim3(1,128,3), blk, 0, stream>>>(jq, jk, jv, 128);
  }
  // Fused attention + entropy
  attn3_k<<<dim3(256), blk, 0, stream>>>(q, kbuf, vbuf, temp, fcp, ffp, out);
  // Edge sigmoid masks + dst histogram
  edge_k<<<dim3(8192), blk, 0, stream>>>(q, kbuf, ei, out + 3408384, emc, cnt);
  // CSR build
  scan_k<<<dim3(1), blk, 0, stream>>>(cnt, off_a, cursor);
  place_k<<<dim3(1024), blk, 0, stream>>>(ei, cursor, elist);
  // GINE gather aggregation
  gine_gather_k<<<dim3(2048), blk, 0, stream>>>(x, ea, ei, emc, off_a, elist, agc, agf);
  // Wo projection
  {
    MJob j0{fcp, nullptr, wfr+OWo, wfr+OWo+16384, bo_v, nullptr, acr};
    MJob j1{ffp, nullptr, wfr+OWo, wfr+OWo+16384, bo_v, nullptr, afr};
    gemm_mfma_k<0,0,0,128><<<dim3(1,128,2), blk, 0, stream>>>(j0, j1, j0, 128);
  }
  // GINE layer 1 (h = x + aggr, relu), N=256
  {
    MJob j0{x, agc, wfr+OWg1, wfr+OWg1+32768, bg1v, nullptr, ghc};
    MJob j1{x, agf, wfr+OWg1, wfr+OWg1+32768, bg1v, nullptr, ghf};
    gemm_mfma_k<1,1,0,128><<<dim3(2,128,2), blk, 0, stream>>>(j0, j1, j0, 256);
  }
  // GINE layer 2, K=256
  {
    MJob j0{ghc, nullptr, wfr+OWg2, wfr+OWg2+32768, bg2v, nullptr, mcr};
    MJob j1{ghf, nullptr, wfr+OWg2, wfr+OWg2+32768, bg2v, nullptr, mfr};
    gemm_mfma_k<0,0,0,256><<<dim3(1,128,2), blk, 0, stream>>>(j0, j1, j0, 128);
  }
  // BN stats round 1: acr, afr, mcr, mfr
  bn_part_k<<<dim3(32,4), dim3(128), 0, stream>>>(acr, afr, mcr, mfr, psum, psq);
  bn_final_k<<<dim3(4), dim3(128), 0, stream>>>(psum, psq,
      g_attn, g_attn, g_mpnn, g_mpnn, be_attn, be_attn, be_mpnn, be_mpnn, ss);
  // Fold BN into Wam + bias
  wam_prep_k<<<dim3(2), dim3(128), 0, stream>>>(Wam, bamv, ss, wfr, biasC, biasF);
  // Fuse linear: concat(bn(attn), bn(mpnn)) @ Wam' + bias'
  {
    MJob j0{acr, mcr, wfr+OWamC, wfr+OWamC+32768, biasC, nullptr, fC};
    MJob j1{afr, mfr, wfr+OWamF, wfr+OWamF+32768, biasF, nullptr, fF};
    gemm_mfma_k<2,0,0,256><<<dim3(1,128,2), blk, 0, stream>>>(j0, j1, j0, 128);
  }
  // Fuse MLP layer 1 (relu), N=256
  {
    MJob j0{fC, nullptr, wfr+OWm1, wfr+OWm1+32768, bm1v, nullptr, fhc};
    MJob j1{fF, nullptr, wfr+OWm1, wfr+OWm1+32768, bm1v, nullptr, fhf};
    gemm_mfma_k<0,1,0,128><<<dim3(2,128,2), blk, 0, stream>>>(j0, j1, j0, 256);
  }
  // Fuse MLP layer 2 + residual, K=256
  {
    MJob j0{fhc, nullptr, wfr+OWm2, wfr+OWm2+32768, bm2v, fC, fmc};
    MJob j1{fhf, nullptr, wfr+OWm2, wfr+OWm2+32768, bm2v, fF, fmf};
    gemm_mfma_k<0,0,1,256><<<dim3(1,128,2), blk, 0, stream>>>(j0, j1, j0, 128);
  }
  // BN stats round 2: fmc, fmf
  bn_part_k<<<dim3(32,2), dim3(128), 0, stream>>>(fmc, fmf, fmc, fmc, psum, psq);
  bn_final_k<<<dim3(2), dim3(128), 0, stream>>>(psum, psq,
      g_mlp, g_mlp, g_mlp, g_mlp, be_mlp, be_mlp, be_mlp, be_mlp, ss + 512);
  // Final features + new_x
  final_k<<<dim3(1024), blk, 0, stream>>>(fmc, fmf, ss + 512, ss + 640, out);
  // Pass-through encodings
  hipMemcpyAsync(out + 3146240, (const void*)cenc, 131072*sizeof(float),
                 hipMemcpyDeviceToDevice, stream);
  hipMemcpyAsync(out + 3277312, (const void*)fenc, 131072*sizeof(float),
                 hipMemcpyDeviceToDevice, stream);
}

// Round 6
// 282.170 us; speedup vs baseline: 1.1862x; 1.1502x over previous
//
#include <hip/hip_runtime.h>

#define TTOK   8192
#define BGR    32
#define NNODE  256
#define DIM    128
#define NH     8
#define HD     16
#define NEDGE  262144
#define SCALE_QK 0.25f

typedef short bf16x8 __attribute__((ext_vector_type(8)));
typedef float f32x4  __attribute__((ext_vector_type(4)));

__device__ __forceinline__ ushort bf_hi(float x, float &rem) {
  unsigned u = __float_as_uint(x) & 0xffff0000u;
  rem = x - __uint_as_float(u);
  return (ushort)(u >> 16);
}
__device__ __forceinline__ ushort bf_rne(float x) {
  unsigned u = __float_as_uint(x);
  u += 0x7fffu + ((u >> 16) & 1u);
  return (ushort)(u >> 16);
}

// ---------------- Weight prep: f32 -> (hi,lo) bf16 in MFMA fragment order ----------------
// frag idx for W[K][N]: ((n/16)*(K/8) + k/8)*128 + (n%16)*8 + (k%8)
struct WArg { const float* w[8]; int K[8]; int nlog[8]; int off[8]; };

__global__ __launch_bounds__(256) void wprep_k(WArg a, ushort* out) {
  const int m = blockIdx.y;
  const int K = a.K[m];
  const int nl = a.nlog[m];
  const int sz = K << nl;
  const int e = blockIdx.x * 256 + threadIdx.x;
  if (e >= sz) return;
  const int k = e >> nl, n = e & ((1 << nl) - 1);
  const float x = a.w[m][e];
  float r;
  const ushort h = bf_hi(x, r);
  const ushort l = bf_rne(r);
  const int idx = (((n >> 4) * (K >> 3) + (k >> 3)) << 7) + ((n & 15) << 3) + (k & 7);
  out[a.off[m] + idx] = h;
  out[a.off[m] + sz + idx] = l;
}

// ---------------- Wam prep (fused bn_final round 1): BN scale/shift folded into weights+bias ----------------
__global__ __launch_bounds__(128) void wam_prep2_k(
    const float* __restrict__ Wam, const float* __restrict__ bam,
    const float* __restrict__ psum, const float* __restrict__ psq,
    const float* __restrict__ gA, const float* __restrict__ bA,
    const float* __restrict__ gM, const float* __restrict__ bM,
    ushort* __restrict__ outbase,
    float* __restrict__ biasC, float* __restrict__ biasF)
{
  const int br = blockIdx.x;                 // 0 = causal, 1 = conf
  __shared__ float2 sA[128], sM[128];
  const int n = threadIdx.x;
  {
    const int ti = br;                       // attn tensor
    float s = 0.f, sq = 0.f;
    for (int c = 0; c < 32; c++) { s += psum[(ti*32 + c)*128 + n]; sq += psq[(ti*32 + c)*128 + n]; }
    const float mean = s * (1.f/8192.f);
    const float var  = sq * (1.f/8192.f) - mean*mean;
    const float istd = rsqrtf(var + 1e-5f);
    const float sc = gA[n] * istd;
    sA[n] = make_float2(sc, bA[n] - mean*sc);
  }
  {
    const int ti = 2 + br;                   // mpnn tensor
    float s = 0.f, sq = 0.f;
    for (int c = 0; c < 32; c++) { s += psum[(ti*32 + c)*128 + n]; sq += psq[(ti*32 + c)*128 + n]; }
    const float mean = s * (1.f/8192.f);
    const float var  = sq * (1.f/8192.f) - mean*mean;
    const float istd = rsqrtf(var + 1e-5f);
    const float sc = gM[n] * istd;
    sM[n] = make_float2(sc, bM[n] - mean*sc);
  }
  __syncthreads();
  ushort* oh = outbase + 393216 + br * 65536;
  ushort* ol = oh + 32768;
  float* bout = br ? biasF : biasC;
  float tacc = 0.f;
  for (int k = 0; k < 256; k++) {
    const float2 st = (k < 128) ? sA[k] : sM[k - 128];
    const float w = Wam[k * 128 + n];
    tacc = fmaf(st.y, w, tacc);
    const float wp = st.x * w;
    float r;
    const ushort h = bf_hi(wp, r);
    const ushort l = bf_rne(r);
    const int idx = (((n >> 4) * 32 + (k >> 3)) << 7) + ((n & 15) << 3) + (k & 7);
    oh[idx] = h; ol[idx] = l;
  }
  bout[n] = bam[n] + tacc;
}

// ---------------- MFMA GEMM (bf16x3 split, no LDS, no barriers) ----------------
struct MJob {
  const float*  A1;
  const float*  A2;
  const ushort* Wh;
  const ushort* Wl;
  const float*  bias;
  const float*  res;
  float*        C;
};

// BM=64, BN=128; 256 thr = 4 waves (2x2); wave = 32 rows x 64 cols (TR=2, TC=4).
// AMODE: 0 = A1 (lda=K); 1 = A1+A2 (lda=128); 2 = concat(A1,A2) (lda=128 each, K=256)
template<int AMODE, int RELU, int HASRES, int K>
__global__ __launch_bounds__(256) void gemm_mfma_k(MJob j0, MJob j1, MJob j2, int N)
{
  const MJob jb = (blockIdx.z == 0) ? j0 : ((blockIdx.z == 1) ? j1 : j2);
  const int tid = threadIdx.x;
  const int w = tid >> 6, lane = tid & 63;
  const int wr = w >> 1, wc = w & 1;
  const int lr = lane & 15, lk = lane >> 4;
  const int bm = blockIdx.y * 64;
  const int bn = blockIdx.x * 128;
  const int row0 = bm + wr * 32 + lr;
  constexpr int K8 = K / 8;
  f32x4 acc[2][4] = {};

  #pragma unroll
  for (int ks = 0; ks < K / 32; ks++) {
    bf16x8 ah[2], al[2];
    #pragma unroll
    for (int rt = 0; rt < 2; rt++) {
      const int row = row0 + rt * 16;
      float av[8];
      if (AMODE == 0) {
        const float* p = jb.A1 + (size_t)row * K + ks * 32 + lk * 8;
        const f32x4 u0 = *(const f32x4*)p;
        const f32x4 u1 = *(const f32x4*)(p + 4);
        av[0]=u0[0]; av[1]=u0[1]; av[2]=u0[2]; av[3]=u0[3];
        av[4]=u1[0]; av[5]=u1[1]; av[6]=u1[2]; av[7]=u1[3];
      } else if (AMODE == 1) {
        const float* p = jb.A1 + (size_t)row * 128 + ks * 32 + lk * 8;
        const float* q = jb.A2 + (size_t)row * 128 + ks * 32 + lk * 8;
        const f32x4 u0 = *(const f32x4*)p;
        const f32x4 u1 = *(const f32x4*)(p + 4);
        const f32x4 v0 = *(const f32x4*)q;
        const f32x4 v1 = *(const f32x4*)(q + 4);
        av[0]=u0[0]+v0[0]; av[1]=u0[1]+v0[1]; av[2]=u0[2]+v0[2]; av[3]=u0[3]+v0[3];
        av[4]=u1[0]+v1[0]; av[5]=u1[1]+v1[1]; av[6]=u1[2]+v1[2]; av[7]=u1[3]+v1[3];
      } else {
        const float* p = (ks * 32 < 128)
          ? jb.A1 + (size_t)row * 128 + ks * 32 + lk * 8
          : jb.A2 + (size_t)row * 128 + (ks * 32 - 128) + lk * 8;
        const f32x4 u0 = *(const f32x4*)p;
        const f32x4 u1 = *(const f32x4*)(p + 4);
        av[0]=u0[0]; av[1]=u0[1]; av[2]=u0[2]; av[3]=u0[3];
        av[4]=u1[0]; av[5]=u1[1]; av[6]=u1[2]; av[7]=u1[3];
      }
      #pragma unroll
      for (int i = 0; i < 8; i++) {
        float r;
        ah[rt][i] = (short)bf_hi(av[i], r);
        al[rt][i] = (short)bf_rne(r);
      }
    }
    #pragma unroll
    for (int ct = 0; ct < 4; ct++) {
      const int ntile = (bn >> 4) + wc * 4 + ct;
      const size_t foff = (((size_t)ntile * K8 + ks * 4 + lk) << 7) + ((size_t)lr << 3);
      const bf16x8 bh = *(const bf16x8*)(jb.Wh + foff);
      const bf16x8 bl = *(const bf16x8*)(jb.Wl + foff);
      #pragma unroll
      for (int rt = 0; rt < 2; rt++) {
        acc[rt][ct] = __builtin_amdgcn_mfma_f32_16x16x32_bf16(ah[rt], bh, acc[rt][ct], 0, 0, 0);
        acc[rt][ct] = __builtin_amdgcn_mfma_f32_16x16x32_bf16(al[rt], bh, acc[rt][ct], 0, 0, 0);
        acc[rt][ct] = __builtin_amdgcn_mfma_f32_16x16x32_bf16(ah[rt], bl, acc[rt][ct], 0, 0, 0);
      }
    }
  }

  #pragma unroll
  for (int ct = 0; ct < 4; ct++) {
    const int col = bn + wc * 64 + ct * 16 + lr;
    const float bb = jb.bias[col];
    #pragma unroll
    for (int rt = 0; rt < 2; rt++) {
      #pragma unroll
      for (int r = 0; r < 4; r++) {
        const int row = bm + wr * 32 + rt * 16 + lk * 4 + r;
        float o = acc[rt][ct][r] + bb;
        if (RELU) o = fmaxf(o, 0.f);
        if (HASRES) o += jb.res[(size_t)row * N + col];
        jb.C[(size_t)row * N + col] = o;
      }
    }
  }
}

// ---------------- Fused attention + edge-mask launch ----------------
// blocks 0..255: attention (one (b,h) each); blocks 256..8447: edge sigmoid masks.
__global__ __launch_bounds__(256) void attn_edge_k(
    const float* __restrict__ q, const float* __restrict__ k, const float* __restrict__ v,
    const float* __restrict__ tptr, float* __restrict__ fc, float* __restrict__ ff,
    const int* __restrict__ ei, float* __restrict__ maskout, float* __restrict__ emc,
    int* __restrict__ cnt, float* __restrict__ dout)
{
  __shared__ float Ks[256][16];
  __shared__ float Vs[256][16];
  __shared__ float red[4][2];
  const int tid = threadIdx.x;

  if (blockIdx.x >= 256) {
    // ---- edge path ----
    const int gt = (blockIdx.x - 256) * 256 + tid;   // 0 .. E*8-1
    const int e = gt >> 3, h = gt & 7;
    const int src = ei[e];
    const int dst = ei[NEDGE + e];
    const float* qr = q + (size_t)src * DIM + h*HD;
    const float* kr = k + (size_t)dst * DIM + h*HD;
    float s = 0.f;
    #pragma unroll
    for (int p = 0; p < 4; p++) {
      float4 a = *(const float4*)(qr + 4*p);
      float4 c = *(const float4*)(kr + 4*p);
      s += a.x*c.x + a.y*c.y + a.z*c.z + a.w*c.w;
    }
    s *= SCALE_QK;
    const float sig = 1.f / (1.f + __expf(-s));
    maskout[gt] = sig;
    float m = sig;
    m += __shfl_xor(m, 1); m += __shfl_xor(m, 2); m += __shfl_xor(m, 4);
    if ((tid & 7) == 0) {
      emc[e] = m * 0.125f;
      atomicAdd(&cnt[dst], 1);
    }
    return;
  }

  // ---- attention path ----
  const int bh = blockIdx.x;
  const int b = bh >> 3, h = bh & 7;
  {
    const float* kr = k + ((size_t)(b*NNODE + tid))*DIM + h*HD;
    const float* vr = v + ((size_t)(b*NNODE + tid))*DIM + h*HD;
    #pragma unroll
    for (int p = 0; p < 4; p++) {
      *(float4*)&Ks[tid][4*p] = *(const float4*)(kr + 4*p);
      *(float4*)&Vs[tid][4*p] = *(const float4*)(vr + 4*p);
    }
  }
  const int pr  = tid >> 1;
  const int par = tid & 1;
  const int r0 = pr * 2;
  const float sc = SCALE_QK / tptr[0];
  float qa[16], qb[16];
  {
    const float* qr = q + ((size_t)(b*NNODE + r0))*DIM + h*HD;
    #pragma unroll
    for (int p = 0; p < 4; p++) {
      float4 a = *(const float4*)(qr + 4*p);
      qa[4*p+0]=a.x*sc; qa[4*p+1]=a.y*sc; qa[4*p+2]=a.z*sc; qa[4*p+3]=a.w*sc;
      float4 c = *(const float4*)(qr + DIM + 4*p);
      qb[4*p+0]=c.x*sc; qb[4*p+1]=c.y*sc; qb[4*p+2]=c.z*sc; qb[4*p+3]=c.w*sc;
    }
  }
  __syncthreads();

  float mxa=-1e30f, mna=1e30f, mxb=-1e30f, mnb=1e30f;
  for (int j = par; j < NNODE; j += 2) {
    const float4 k0 = *(const float4*)&Ks[j][0];
    const float4 k1 = *(const float4*)&Ks[j][4];
    const float4 k2 = *(const float4*)&Ks[j][8];
    const float4 k3 = *(const float4*)&Ks[j][12];
    float sa = qa[0]*k0.x; float sb = qb[0]*k0.x;
    sa = fmaf(qa[1],k0.y,sa); sb = fmaf(qb[1],k0.y,sb);
    sa = fmaf(qa[2],k0.z,sa); sb = fmaf(qb[2],k0.z,sb);
    sa = fmaf(qa[3],k0.w,sa); sb = fmaf(qb[3],k0.w,sb);
    sa = fmaf(qa[4],k1.x,sa); sb = fmaf(qb[4],k1.x,sb);
    sa = fmaf(qa[5],k1.y,sa); sb = fmaf(qb[5],k1.y,sb);
    sa = fmaf(qa[6],k1.z,sa); sb = fmaf(qb[6],k1.z,sb);
    sa = fmaf(qa[7],k1.w,sa); sb = fmaf(qb[7],k1.w,sb);
    sa = fmaf(qa[8],k2.x,sa); sb = fmaf(qb[8],k2.x,sb);
    sa = fmaf(qa[9],k2.y,sa); sb = fmaf(qb[9],k2.y,sb);
    sa = fmaf(qa[10],k2.z,sa); sb = fmaf(qb[10],k2.z,sb);
    sa = fmaf(qa[11],k2.w,sa); sb = fmaf(qb[11],k2.w,sb);
    sa = fmaf(qa[12],k3.x,sa); sb = fmaf(qb[12],k3.x,sb);
    sa = fmaf(qa[13],k3.y,sa); sb = fmaf(qb[13],k3.y,sb);
    sa = fmaf(qa[14],k3.z,sa); sb = fmaf(qb[14],k3.z,sb);
    sa = fmaf(qa[15],k3.w,sa); sb = fmaf(qb[15],k3.w,sb);
    mxa = fmaxf(mxa, sa); mna = fminf(mna, sa);
    mxb = fmaxf(mxb, sb); mnb = fminf(mnb, sb);
  }
  mxa = fmaxf(mxa, __shfl_xor(mxa, 1)); mna = fminf(mna, __shfl_xor(mna, 1));
  mxb = fmaxf(mxb, __shfl_xor(mxb, 1)); mnb = fminf(mnb, __shfl_xor(mnb, 1));

  float zca=0,zfa=0,Eca=0,Efa=0, zcb=0,zfb=0,Ecb=0,Efb=0;
  float oca[16], ofa[16], ocb[16], ofb[16];
  #pragma unroll
  for (int d = 0; d < 16; d++) { oca[d]=0.f; ofa[d]=0.f; ocb[d]=0.f; ofb[d]=0.f; }
  for (int j = par; j < NNODE; j += 2) {
    const float4 k0 = *(const float4*)&Ks[j][0];
    const float4 k1 = *(const float4*)&Ks[j][4];
    const float4 k2 = *(const float4*)&Ks[j][8];
    const float4 k3 = *(const float4*)&Ks[j][12];
    float sa = qa[0]*k0.x; float sb = qb[0]*k0.x;
    sa = fmaf(qa[1],k0.y,sa); sb = fmaf(qb[1],k0.y,sb);
    sa = fmaf(qa[2],k0.z,sa); sb = fmaf(qb[2],k0.z,sb);
    sa = fmaf(qa[3],k0.w,sa); sb = fmaf(qb[3],k0.w,sb);
    sa = fmaf(qa[4],k1.x,sa); sb = fmaf(qb[4],k1.x,sb);
    sa = fmaf(qa[5],k1.y,sa); sb = fmaf(qb[5],k1.y,sb);
    sa = fmaf(qa[6],k1.z,sa); sb = fmaf(qb[6],k1.z,sb);
    sa = fmaf(qa[7],k1.w,sa); sb = fmaf(qb[7],k1.w,sb);
    sa = fmaf(qa[8],k2.x,sa); sb = fmaf(qb[8],k2.x,sb);
    sa = fmaf(qa[9],k2.y,sa); sb = fmaf(qb[9],k2.y,sb);
    sa = fmaf(qa[10],k2.z,sa); sb = fmaf(qb[10],k2.z,sb);
    sa = fmaf(qa[11],k2.w,sa); sb = fmaf(qb[11],k2.w,sb);
    sa = fmaf(qa[12],k3.x,sa); sb = fmaf(qb[12],k3.x,sb);
    sa = fmaf(qa[13],k3.y,sa); sb = fmaf(qb[13],k3.y,sb);
    sa = fmaf(qa[14],k3.z,sa); sb = fmaf(qb[14],k3.z,sb);
    sa = fmaf(qa[15],k3.w,sa); sb = fmaf(qb[15],k3.w,sb);
    const float eca = __expf(sa - mxa);
    const float efa = __expf(mna - sa);
    const float ecb = __expf(sb - mxb);
    const float efb = __expf(mnb - sb);
    zca += eca; zfa += efa; zcb += ecb; zfb += efb;
    Eca = fmaf(eca, sa, Eca); Efa = fmaf(efa, -sa, Efa);
    Ecb = fmaf(ecb, sb, Ecb); Efb = fmaf(efb, -sb, Efb);
    const float4 v0 = *(const float4*)&Vs[j][0];
    const float4 v1 = *(const float4*)&Vs[j][4];
    const float4 v2 = *(const float4*)&Vs[j][8];
    const float4 v3 = *(const float4*)&Vs[j][12];
    const float vv[16] = {v0.x,v0.y,v0.z,v0.w, v1.x,v1.y,v1.z,v1.w,
                          v2.x,v2.y,v2.z,v2.w, v3.x,v3.y,v3.z,v3.w};
    #pragma unroll
    for (int d = 0; d < 16; d++) {
      oca[d] = fmaf(eca, vv[d], oca[d]);
      ofa[d] = fmaf(efa, vv[d], ofa[d]);
      ocb[d] = fmaf(ecb, vv[d], ocb[d]);
      ofb[d] = fmaf(efb, vv[d], ofb[d]);
    }
  }
  zca += __shfl_xor(zca, 1); zfa += __shfl_xor(zfa, 1);
  zcb += __shfl_xor(zcb, 1); zfb += __shfl_xor(zfb, 1);
  Eca += __shfl_xor(Eca, 1); Efa += __shfl_xor(Efa, 1);
  Ecb += __shfl_xor(Ecb, 1); Efb += __shfl_xor(Efb, 1);
  #pragma unroll
  for (int d = 0; d < 16; d++) {
    oca[d] += __shfl_xor(oca[d], 1);
    ofa[d] += __shfl_xor(ofa[d], 1);
    ocb[d] += __shfl_xor(ocb[d], 1);
    ofb[d] += __shfl_xor(ofb[d], 1);
  }
  float entc = 0.f, entf = 0.f;
  if (par == 0) {
    const float rca = 1.f/zca, rfa = 1.f/zfa, rcb = 1.f/zcb, rfb = 1.f/zfb;
    entc = (mxa + __logf(zca) - Eca*rca) + (mxb + __logf(zcb) - Ecb*rcb);
    entf = (-mna + __logf(zfa) - Efa*rfa) + (-mnb + __logf(zfb) - Efb*rfb);
    float* pc = fc + ((size_t)(b*NNODE + r0))*DIM + h*HD;
    float* pf = ff + ((size_t)(b*NNODE + r0))*DIM + h*HD;
    #pragma unroll
    for (int p = 0; p < 4; p++) {
      *(float4*)(pc + 4*p)       = make_float4(oca[4*p]*rca, oca[4*p+1]*rca, oca[4*p+2]*rca, oca[4*p+3]*rca);
      *(float4*)(pc + DIM + 4*p) = make_float4(ocb[4*p]*rcb, ocb[4*p+1]*rcb, ocb[4*p+2]*rcb, ocb[4*p+3]*rcb);
      *(float4*)(pf + 4*p)       = make_float4(ofa[4*p]*rfa, ofa[4*p+1]*rfa, ofa[4*p+2]*rfa, ofa[4*p+3]*rfa);
      *(float4*)(pf + DIM + 4*p) = make_float4(ofb[4*p]*rfb, ofb[4*p+1]*rfb, ofb[4*p+2]*rfb, ofb[4*p+3]*rfb);
    }
  }
  #pragma unroll
  for (int off = 1; off < 64; off <<= 1) {
    entc += __shfl_xor(entc, off);
    entf += __shfl_xor(entf, off);
  }
  const int wv = tid >> 6;
  if ((tid & 63) == 0) { red[wv][0] = entc; red[wv][1] = entf; }
  __syncthreads();
  if (tid == 0) {
    const float tc = red[0][0]+red[1][0]+red[2][0]+red[3][0];
    const float tf = red[0][1]+red[1][1]+red[2][1]+red[3][1];
    dout[3145728 + bh] = tc * (1.0f/256.0f);
    dout[3145984 + bh] = tf * (1.0f/256.0f);
  }
}

// ---------------- CSR build ----------------
__global__ __launch_bounds__(256) void scan_k(const int* __restrict__ cnt,
                                              int* __restrict__ off,
                                              int* __restrict__ cursor)
{
  __shared__ int part[256];
  const int t = threadIdx.x;
  const int base = t * 32;
  int local[32];
  int s = 0;
  #pragma unroll
  for (int i = 0; i < 32; i++) { local[i] = s; s += cnt[base + i]; }
  part[t] = s;
  __syncthreads();
  int pre = 0;
  for (int i = 0; i < t; i++) pre += part[i];
  #pragma unroll
  for (int i = 0; i < 32; i++) {
    const int v = pre + local[i];
    off[base + i] = v;
    cursor[base + i] = v;
  }
  if (t == 255) off[8192] = pre + s;
}

// place: write dst-sorted metadata record {src, e, m} (16B) per edge
__global__ __launch_bounds__(256) void place2_k(const int* __restrict__ ei,
                                                const float* __restrict__ emc,
                                                int* __restrict__ cursor,
                                                int4* __restrict__ meta)
{
  const int e = blockIdx.x * 256 + threadIdx.x;
  const int d = ei[NEDGE + e];
  const int pos = atomicAdd(&cursor[d], 1);
  meta[pos] = make_int4(ei[e], e, __float_as_int(emc[e]), 0);
}

// ---------------- GINE gather-aggregate (one wave per node, 16B metadata) ----------------
__global__ __launch_bounds__(256) void gine_gather_k(
    const float* __restrict__ x, const float* __restrict__ ea,
    const int* __restrict__ off, const int4* __restrict__ meta,
    float* __restrict__ aggrC, float* __restrict__ aggrF)
{
  const int wv = threadIdx.x >> 6, lane = threadIdx.x & 63;
  const int eh = lane >> 5;
  const int c4 = (lane & 31) * 4;
  const int n = blockIdx.x * 4 + wv;
  float4 aC = make_float4(0,0,0,0), aF = make_float4(0,0,0,0);
  int i = off[n] + eh;
  const int end = off[n + 1];
  if (i < end) {
    int4 md = meta[i];
    float4 u = *(const float4*)(x  + (size_t)md.x * DIM + c4);
    float4 w = *(const float4*)(ea + (size_t)md.y * DIM + c4);
    int inext = i + 2;
    for (;;) {
      const bool more = inext < end;
      int4 mdn = make_int4(0,0,0,0);
      float4 un = make_float4(0,0,0,0), wn = make_float4(0,0,0,0);
      if (more) {
        mdn = meta[inext];
        un = *(const float4*)(x  + (size_t)mdn.x * DIM + c4);
        wn = *(const float4*)(ea + (size_t)mdn.y * DIM + c4);
      }
      const float mc = __int_as_float(md.z);
      const float mf = 1.f - mc;
      const float g0 = fmaxf(u.x + w.x, 0.f);
      const float g1 = fmaxf(u.y + w.y, 0.f);
      const float g2 = fmaxf(u.z + w.z, 0.f);
      const float g3 = fmaxf(u.w + w.w, 0.f);
      aC.x = fmaf(g0, mc, aC.x); aC.y = fmaf(g1, mc, aC.y);
      aC.z = fmaf(g2, mc, aC.z); aC.w = fmaf(g3, mc, aC.w);
      aF.x = fmaf(g0, mf, aF.x); aF.y = fmaf(g1, mf, aF.y);
      aF.z = fmaf(g2, mf, aF.z); aF.w = fmaf(g3, mf, aF.w);
      if (!more) break;
      md = mdn; u = un; w = wn; inext += 2;
    }
  }
  aC.x += __shfl_xor(aC.x, 32); aC.y += __shfl_xor(aC.y, 32);
  aC.z += __shfl_xor(aC.z, 32); aC.w += __shfl_xor(aC.w, 32);
  aF.x += __shfl_xor(aF.x, 32); aF.y += __shfl_xor(aF.y, 32);
  aF.z += __shfl_xor(aF.z, 32); aF.w += __shfl_xor(aF.w, 32);
  if (eh == 0) *(float4*)(aggrC + (size_t)n * DIM + c4) = aC;
  else         *(float4*)(aggrF + (size_t)n * DIM + c4) = aF;
}

// ---------------- BatchNorm partial stats ----------------
__global__ __launch_bounds__(128) void bn_part_k(
    const float* X0, const float* X1, const float* X2, const float* X3,
    float* __restrict__ psum, float* __restrict__ psq)
{
  const int ti = blockIdx.y, chunk = blockIdx.x, col = threadIdx.x;
  const float* X = (ti == 0) ? X0 : (ti == 1) ? X1 : (ti == 2) ? X2 : X3;
  const float* p = X + (size_t)chunk * 256 * DIM + col;
  float s = 0.f, sq = 0.f;
  for (int r = 0; r < 256; r++) {
    const float xv = p[(size_t)r * DIM];
    s += xv; sq += xv * xv;
  }
  psum[(ti*32 + chunk)*DIM + col] = s;
  psq [(ti*32 + chunk)*DIM + col] = sq;
}

// ---------------- Final outputs (fused bn_final round 2 + encoding pass-through) ----------------
__global__ __launch_bounds__(256) void final2_k(
    const float* __restrict__ fmc, const float* __restrict__ fmf,
    const float* __restrict__ psum, const float* __restrict__ psq,
    const float* __restrict__ g_mlp, const float* __restrict__ be_mlp,
    const float* __restrict__ cenc, const float* __restrict__ fenc,
    float* __restrict__ dout)
{
  const int bx = blockIdx.x;
  const int tid = threadIdx.x;
  if (bx >= 1024) {
    const int i = (bx - 1024) * 256 + tid;   // 0..32767 float4s
    const float4 c = ((const float4*)cenc)[i];
    const float4 f = ((const float4*)fenc)[i];
    ((float4*)(dout + 3146240))[i] = c;
    ((float4*)(dout + 3277312))[i] = f;
    return;
  }
  __shared__ float2 sst[256];
  {
    const int ti = tid >> 7;          // 0 = causal, 1 = conf
    const int col = tid & 127;
    float s = 0.f, sq = 0.f;
    for (int c = 0; c < 32; c++) { s += psum[(ti*32 + c)*128 + col]; sq += psq[(ti*32 + c)*128 + col]; }
    const float mean = s * (1.f/8192.f);
    const float var  = sq * (1.f/8192.f) - mean*mean;
    const float istd = rsqrtf(var + 1e-5f);
    const float sc = g_mlp[col] * istd;
    sst[tid] = make_float2(sc, be_mlp[col] - mean*sc);
  }
  __syncthreads();
  const int idx4 = bx * 256 + tid;   // 0..262143
  const int base = idx4 * 4;
  const int col = base & 127;
  const float4 a = *(const float4*)(fmc + base);
  const float4 b = *(const float4*)(fmf + base);
  const float2 s0 = sst[col],     s1 = sst[col+1],     s2 = sst[col+2],     s3 = sst[col+3];
  const float2 t0 = sst[128+col], t1 = sst[128+col+1], t2 = sst[128+col+2], t3 = sst[128+col+3];
  const float c0 = a.x*s0.x + s0.y, c1 = a.y*s1.x + s1.y, c2 = a.z*s2.x + s2.y, c3 = a.w*s3.x + s3.y;
  const float f0 = b.x*t0.x + t0.y, f1 = b.y*t1.x + t1.y, f2 = b.z*t2.x + t2.y, f3 = b.w*t3.x + t3.y;
  *(float4*)(dout + 1048576 + base) = make_float4(c0,c1,c2,c3);
  *(float4*)(dout + 2097152 + base) = make_float4(f0,f1,f2,f3);
  *(float4*)(dout + base) = make_float4(0.5f*(c0+f0), 0.5f*(c1+f1), 0.5f*(c2+f2), 0.5f*(c3+f3));
}

// ---------------- Launcher ----------------
extern "C" void kernel_launch(void* const* d_in, const int* in_sizes, int n_in,
                              void* d_out, int out_size, void* d_ws, size_t ws_size,
                              hipStream_t stream)
{
  const float* x    = (const float*)d_in[0];
  const int*   ei   = (const int*)  d_in[2];
  const float* ea   = (const float*)d_in[3];
  const float* temp = (const float*)d_in[4];
  const float* cenc = (const float*)d_in[5];
  const float* fenc = (const float*)d_in[6];
  const float* Wq   = (const float*)d_in[7];
  const float* bq_v = (const float*)d_in[8];
  const float* Wk   = (const float*)d_in[9];
  const float* bk_v = (const float*)d_in[10];
  const float* Wv   = (const float*)d_in[11];
  const float* bv_v = (const float*)d_in[12];
  const float* Wo   = (const float*)d_in[13];
  const float* bo_v = (const float*)d_in[14];
  const float* Wg1  = (const float*)d_in[15];
  const float* bg1v = (const float*)d_in[16];
  const float* Wg2  = (const float*)d_in[17];
  const float* bg2v = (const float*)d_in[18];
  const float* Wam  = (const float*)d_in[19];
  const float* bamv = (const float*)d_in[20];
  const float* Wm1  = (const float*)d_in[21];
  const float* bm1v = (const float*)d_in[22];
  const float* Wm2  = (const float*)d_in[23];
  const float* bm2v = (const float*)d_in[24];
  const float* g_attn  = (const float*)d_in[25];
  const float* be_attn = (const float*)d_in[26];
  const float* g_mpnn  = (const float*)d_in[27];
  const float* be_mpnn = (const float*)d_in[28];
  const float* g_mlp   = (const float*)d_in[29];
  const float* be_mlp  = (const float*)d_in[30];

  float* out = (float*)d_out;
  float* ws  = (float*)d_ws;
  const size_t M1 = 1048576;

  float* q    = ws + 0*M1;
  float* kbuf = ws + 1*M1;
  float* vbuf = ws + 2*M1;
  float* fcp  = ws + 3*M1;
  float* ffp  = ws + 4*M1;
  float* acr  = ws + 5*M1;
  float* afr  = ws + 6*M1;
  float* agc  = ws + 7*M1;
  float* agf  = ws + 8*M1;
  float* ghc  = ws + 9*M1;    // 2M floats (CSR ints live here pre-GINE1)
  float* ghf  = ws + 11*M1;   // 2M
  float* emc  = ws + 13*M1;            // 262144
  float* psum = emc + 262144;          // 16384
  float* psq  = psum + 16384;          // 16384
  float* biasC = psq + 16384;          // 128
  float* biasF = biasC + 128;          // 128
  ushort* wfr = (ushort*)(ws + 14*M1); // 524288 ushorts (1MB)
  int4* meta  = (int4*)(ws + 16*M1);   // 262144 * 16B = 4MB
  int* cnt    = (int*)(ws + 9*M1);
  int* off_a  = cnt + 8192;
  int* cursor = off_a + 8200;
  // reuses (sequenced by stream order)
  float* mcr = q;
  float* mfr = kbuf;
  float* fC  = vbuf;
  float* fF  = fcp;
  float* fhc = ghc;
  float* fhf = ghf;
  float* fmc = ffp;
  float* fmf = agc;

  // weight frag offsets (ushorts): [hi | lo] per matrix
  const int OWq = 0, OWk = 32768, OWv = 65536, OWo = 98304;
  const int OWg1 = 131072, OWg2 = 196608, OWm1 = 262144, OWm2 = 327680;
  const int OWamC = 393216, OWamF = 458752;

  hipMemsetAsync(cnt, 0, 8192*sizeof(int), stream);

  const dim3 blk(256);

  // Weight prep (all except Wam)
  {
    WArg a;
    a.w[0]=Wq;  a.K[0]=128; a.nlog[0]=7; a.off[0]=OWq;
    a.w[1]=Wk;  a.K[1]=128; a.nlog[1]=7; a.off[1]=OWk;
    a.w[2]=Wv;  a.K[2]=128; a.nlog[2]=7; a.off[2]=OWv;
    a.w[3]=Wo;  a.K[3]=128; a.nlog[3]=7; a.off[3]=OWo;
    a.w[4]=Wg1; a.K[4]=128; a.nlog[4]=8; a.off[4]=OWg1;
    a.w[5]=Wg2; a.K[5]=256; a.nlog[5]=7; a.off[5]=OWg2;
    a.w[6]=Wm1; a.K[6]=128; a.nlog[6]=8; a.off[6]=OWm1;
    a.w[7]=Wm2; a.K[7]=256; a.nlog[7]=7; a.off[7]=OWm2;
    wprep_k<<<dim3(128, 8), blk, 0, stream>>>(a, wfr);
  }
  // QKV projections
  {
    MJob jq{x, nullptr, wfr+OWq, wfr+OWq+16384, bq_v, nullptr, q};
    MJob jk{x, nullptr, wfr+OWk, wfr+OWk+16384, bk_v, nullptr, kbuf};
    MJob jv{x, nullptr, wfr+OWv, wfr+OWv+16384, bv_v, nullptr, vbuf};
    gemm_mfma_k<0,0,0,128><<<dim3(1,128,3), blk, 0, stream>>>(jq, jk, jv, 128);
  }
  // Fused attention + entropy + edge masks + dst histogram (one launch)
  attn_edge_k<<<dim3(8448), blk, 0, stream>>>(q, kbuf, vbuf, temp, fcp, ffp,
                                              ei, out + 3408384, emc, cnt, out);
  // CSR build with inline metadata
  scan_k<<<dim3(1), blk, 0, stream>>>(cnt, off_a, cursor);
  place2_k<<<dim3(1024), blk, 0, stream>>>(ei, emc, cursor, meta);
  // GINE gather aggregation
  gine_gather_k<<<dim3(2048), blk, 0, stream>>>(x, ea, off_a, meta, agc, agf);
  // Wo projection
  {
    MJob j0{fcp, nullptr, wfr+OWo, wfr+OWo+16384, bo_v, nullptr, acr};
    MJob j1{ffp, nullptr, wfr+OWo, wfr+OWo+16384, bo_v, nullptr, afr};
    gemm_mfma_k<0,0,0,128><<<dim3(1,128,2), blk, 0, stream>>>(j0, j1, j0, 128);
  }
  // GINE layer 1 (h = x + aggr, relu), N=256
  {
    MJob j0{x, agc, wfr+OWg1, wfr+OWg1+32768, bg1v, nullptr, ghc};
    MJob j1{x, agf, wfr+OWg1, wfr+OWg1+32768, bg1v, nullptr, ghf};
    gemm_mfma_k<1,1,0,128><<<dim3(2,128,2), blk, 0, stream>>>(j0, j1, j0, 256);
  }
  // GINE layer 2, K=256
  {
    MJob j0{ghc, nullptr, wfr+OWg2, wfr+OWg2+32768, bg2v, nullptr, mcr};
    MJob j1{ghf, nullptr, wfr+OWg2, wfr+OWg2+32768, bg2v, nullptr, mfr};
    gemm_mfma_k<0,0,0,256><<<dim3(1,128,2), blk, 0, stream>>>(j0, j1, j0, 128);
  }
  // BN stats round 1: acr, afr, mcr, mfr
  bn_part_k<<<dim3(32,4), dim3(128), 0, stream>>>(acr, afr, mcr, mfr, psum, psq);
  // Fold BN into Wam + bias (fused bn_final round 1)
  wam_prep2_k<<<dim3(2), dim3(128), 0, stream>>>(Wam, bamv, psum, psq,
      g_attn, be_attn, g_mpnn, be_mpnn, wfr, biasC, biasF);
  // Fuse linear: concat(bn(attn), bn(mpnn)) @ Wam' + bias'
  {
    MJob j0{acr, mcr, wfr+OWamC, wfr+OWamC+32768, biasC, nullptr, fC};
    MJob j1{afr, mfr, wfr+OWamF, wfr+OWamF+32768, biasF, nullptr, fF};
    gemm_mfma_k<2,0,0,256><<<dim3(1,128,2), blk, 0, stream>>>(j0, j1, j0, 128);
  }
  // Fuse MLP layer 1 (relu), N=256
  {
    MJob j0{fC, nullptr, wfr+OWm1, wfr+OWm1+32768, bm1v, nullptr, fhc};
    MJob j1{fF, nullptr, wfr+OWm1, wfr+OWm1+32768, bm1v, nullptr, fhf};
    gemm_mfma_k<0,1,0,128><<<dim3(2,128,2), blk, 0, stream>>>(j0, j1, j0, 256);
  }
  // Fuse MLP layer 2 + residual, K=256
  {
    MJob j0{fhc, nullptr, wfr+OWm2, wfr+OWm2+32768, bm2v, fC, fmc};
    MJob j1{fhf, nullptr, wfr+OWm2, wfr+OWm2+32768, bm2v, fF, fmf};
    gemm_mfma_k<0,0,1,256><<<dim3(1,128,2), blk, 0, stream>>>(j0, j1, j0, 128);
  }
  // BN stats round 2: fmc, fmf
  bn_part_k<<<dim3(32,2), dim3(128), 0, stream>>>(fmc, fmf, fmc, fmc, psum, psq);
  // Final features + new_x + encoding pass-through (fused bn_final round 2)
  final2_k<<<dim3(1152), blk, 0, stream>>>(fmc, fmf, psum, psq, g_mlp, be_mlp,
                                           cenc, fenc, out);
}